// Round 7
// baseline (859.897 us; speedup 1.0000x reference)
//
#include <hip/hip_runtime.h>

typedef unsigned short u16;
typedef unsigned int   u32;

// Problem: B=8, C=256, N=4096 (16^3), heads=8, d=32, P=64.
// Inputs: fp32 (auto-detected; canonicalized x->bf16, weights/EF/temps->fp32).
// OUTPUT: FP32 (reference's output dtype is float32 — the bf16-grid refmax in
// round 0 was an artifact of the reference being COMPUTED in bf16).
// Algebra: faithful to the jax text: q=W[0:256],k=W[256:512],v_sa=W[768:1024],
// EF indexed [n,p], SA merged via the text's scramble, CA natural.

__device__ __forceinline__ float bf2f(u16 u){
  union { u32 i; float f; } v; v.i = ((u32)u) << 16; return v.f;
}
__device__ __forceinline__ u16 f2bf(float f){
  u32 u = __float_as_uint(f);
  u32 r = u + 0x7FFFu + ((u >> 16) & 1u);   // RNE
  return (u16)(r >> 16);
}

// ---------------------------------------------------------------------------
// K0a: dtype detector on x. flag=1 => fp32 input.
// ---------------------------------------------------------------------------
__global__ void k_detect(const u16* __restrict__ x, u32* __restrict__ flag){
  __shared__ int cnt[256];
  const int t = threadIdx.x;
  int c = 0;
  #pragma unroll
  for(int i = 0; i < 4; i++){
    u16 v = x[t * 4 + i];
    int e = (v >> 7) & 0xFF;
    if(e >= 112 && e <= 134) c++;
  }
  cnt[t] = c;
  __syncthreads();
  for(int s = 128; s > 0; s >>= 1){
    if(t < s) cnt[t] += cnt[t + s];
    __syncthreads();
  }
  if(t == 0) *flag = (cnt[0] < 800) ? 1u : 0u;
}

// ---------------------------------------------------------------------------
// K0b: canonicalize x to bf16 (8 elems/thread).
// ---------------------------------------------------------------------------
__global__ __launch_bounds__(256) void k_conv_bf(const void* __restrict__ src,
                                                 u16* __restrict__ dst, int n,
                                                 const u32* __restrict__ flag){
  const int i0 = (blockIdx.x * 256 + threadIdx.x) * 8;
  if(i0 >= n) return;
  const bool isf32 = (*flag != 0);
  if(isf32){
    const float4 a = *(const float4*)((const float*)src + i0);
    const float4 b = *(const float4*)((const float*)src + i0 + 4);
    uint4 o;
    o.x = (u32)f2bf(a.x) | ((u32)f2bf(a.y) << 16);
    o.y = (u32)f2bf(a.z) | ((u32)f2bf(a.w) << 16);
    o.z = (u32)f2bf(b.x) | ((u32)f2bf(b.y) << 16);
    o.w = (u32)f2bf(b.z) | ((u32)f2bf(b.w) << 16);
    *(uint4*)(dst + i0) = o;
  } else {
    *(uint4*)(dst + i0) = *(const uint4*)((const u16*)src + i0);
  }
}

// ---------------------------------------------------------------------------
// K0c: canonicalize weights/EF/temps to fp32 (4 elems/thread).
// ---------------------------------------------------------------------------
__global__ __launch_bounds__(256) void k_conv_f32(const void* __restrict__ src,
                                                  float* __restrict__ dst, int n,
                                                  const u32* __restrict__ flag){
  const int i0 = (blockIdx.x * 256 + threadIdx.x) * 4;
  if(i0 >= n) return;
  const bool isf32 = (*flag != 0);
  if(isf32){
    *(float4*)(dst + i0) = *(const float4*)((const float*)src + i0);
  } else {
    const uint2 a = *(const uint2*)((const u16*)src + i0);
    float4 o;
    o.x = bf2f((u16)(a.x & 0xFFFF)); o.y = bf2f((u16)(a.x >> 16));
    o.z = bf2f((u16)(a.y & 0xFFFF)); o.w = bf2f((u16)(a.y >> 16));
    *(float4*)(dst + i0) = o;
  }
}

// ---------------------------------------------------------------------------
// K1: Y[b, m0+i, n] = sum_c Wf[m0+i, c] * xb[b, c, n], 4 rows/block, full n.
// ---------------------------------------------------------------------------
__global__ __launch_bounds__(256) void k_gemm4(const float* __restrict__ Wf,
                                               const u16* __restrict__ xb,
                                               u16* __restrict__ Y,
                                               int rows_per_b){
  const int m0 = blockIdx.x * 4, b = blockIdx.y;
  const int t = threadIdx.x, n0 = t * 16;
  float acc[4][16] = {};
  const float* w0 = Wf + (size_t)m0 * 256;
  for(int c = 0; c < 256; c++){
    const u16* xp = xb + (size_t)(b * 256 + c) * 4096 + n0;
    const uint4 xa = *(const uint4*)xp;
    const uint4 xc = *(const uint4*)(xp + 8);
    float xv[16];
    const u32 w[8] = {xa.x, xa.y, xa.z, xa.w, xc.x, xc.y, xc.z, xc.w};
    #pragma unroll
    for(int q = 0; q < 8; q++){
      xv[2*q]   = bf2f((u16)(w[q] & 0xFFFF));
      xv[2*q+1] = bf2f((u16)(w[q] >> 16));
    }
    const float w_0 = w0[c], w_1 = w0[256 + c], w_2 = w0[512 + c], w_3 = w0[768 + c];
    #pragma unroll
    for(int k = 0; k < 16; k++){
      acc[0][k] += w_0 * xv[k];
      acc[1][k] += w_1 * xv[k];
      acc[2][k] += w_2 * xv[k];
      acc[3][k] += w_3 * xv[k];
    }
  }
  #pragma unroll
  for(int i = 0; i < 4; i++){
    uint4 o0, o1;
    o0.x = (u32)f2bf(acc[i][0])  | ((u32)f2bf(acc[i][1])  << 16);
    o0.y = (u32)f2bf(acc[i][2])  | ((u32)f2bf(acc[i][3])  << 16);
    o0.z = (u32)f2bf(acc[i][4])  | ((u32)f2bf(acc[i][5])  << 16);
    o0.w = (u32)f2bf(acc[i][6])  | ((u32)f2bf(acc[i][7])  << 16);
    o1.x = (u32)f2bf(acc[i][8])  | ((u32)f2bf(acc[i][9])  << 16);
    o1.y = (u32)f2bf(acc[i][10]) | ((u32)f2bf(acc[i][11]) << 16);
    o1.z = (u32)f2bf(acc[i][12]) | ((u32)f2bf(acc[i][13]) << 16);
    o1.w = (u32)f2bf(acc[i][14]) | ((u32)f2bf(acc[i][15]) << 16);
    u16* yp = Y + (size_t)(b * rows_per_b + m0 + i) * 4096 + n0;
    *(uint4*)yp = o0;
    *(uint4*)(yp + 8) = o1;
  }
}

// ---------------------------------------------------------------------------
// K2: xef[b,c,p] = sum_n xb[b,c,n] * EFf[n,p].  Block: 4 c x 64 p.
// ---------------------------------------------------------------------------
__global__ __launch_bounds__(256) void k_xef4(const u16* __restrict__ xb,
                                              const float* __restrict__ EFf,
                                              float* __restrict__ xef){
  const int t = threadIdx.x;
  const int ci = t >> 6, p = t & 63;
  const int c = blockIdx.x * 4 + ci, b = blockIdx.y;
  const u16* xr = xb + (size_t)(b * 256 + c) * 4096;
  float acc = 0.f;
  for(int n = 0; n < 4096; n++)
    acc += bf2f(xr[n]) * EFf[(size_t)n * 64 + p];
  xef[(size_t)(b * 256 + c) * 64 + p] = acc;
}

// ---------------------------------------------------------------------------
// K3: kvp[b, r, p] = sum_c W_sa[row_w(r), c] * xef[b, c, p]
// r in [0,256): k rows (W_sa 256:512); r in [256,512): v rows (W_sa 768:1024).
// ---------------------------------------------------------------------------
__global__ __launch_bounds__(256) void k_kv4(const float* __restrict__ Wsaf,
                                             const float* __restrict__ xef,
                                             float* __restrict__ kvp){
  const int t = threadIdx.x;
  const int ri = t >> 6, p = t & 63;
  const int r = blockIdx.x * 4 + ri, b = blockIdx.y;
  const int row_w = (r < 256) ? (256 + r) : (512 + r);
  const float* wr = Wsaf + (size_t)row_w * 256;
  const float* xr = xef + (size_t)(b * 256) * 64 + p;
  float acc = 0.f;
  for(int c = 0; c < 256; c++)
    acc += wr[c] * xr[(size_t)c * 64];
  kvp[(size_t)(b * 512 + r) * 64 + p] = acc;
}

// ---------------------------------------------------------------------------
// K4: dst[b*256+r] = 1 / max(||row||_2, 1e-12), LDS tree reduction.
// ---------------------------------------------------------------------------
__global__ __launch_bounds__(256) void k_norm(const u16* __restrict__ src,
                                              float* __restrict__ dst,
                                              int stride_b, int row_off){
  __shared__ float red[256];
  const int r = blockIdx.x, b = blockIdx.y, t = threadIdx.x;
  const u16* row = src + (size_t)(b * stride_b + row_off + r) * 4096;
  float s = 0.f;
  #pragma unroll
  for(int i = 0; i < 16; i++){ float v = bf2f(row[t + 256 * i]); s += v * v; }
  red[t] = s;
  __syncthreads();
  for(int s2 = 128; s2 > 0; s2 >>= 1){
    if(t < s2) red[t] += red[t + s2];
    __syncthreads();
  }
  if(t == 0) dst[b * 256 + r] = 1.0f / fmaxf(sqrtf(red[0]), 1e-12f);
}

// ---------------------------------------------------------------------------
// K5: Gram partials over n-split s: Gp[s][b][h][j][e] = sum_n qc[j,n]*kc[e,n].
// ---------------------------------------------------------------------------
__global__ __launch_bounds__(256) void k_gram8(const u16* __restrict__ y_sc,
                                               float* __restrict__ Gp){
  const int t = threadIdx.x;
  const int s = blockIdx.x, h = blockIdx.y, b = blockIdx.z;
  const int j = t >> 3, e0 = (t & 7) * 4;
  const u16* qr = y_sc + (size_t)(b * 768 + h * 32 + j) * 4096;
  const u16* k0 = y_sc + (size_t)(b * 768 + 256 + h * 32 + e0) * 4096;
  float acc[4] = {};
  for(int n = s * 512; n < s * 512 + 512; n++){
    const float qv = bf2f(qr[n]);
    acc[0] += qv * bf2f(k0[n]);
    acc[1] += qv * bf2f(k0[n + 4096]);
    acc[2] += qv * bf2f(k0[n + 8192]);
    acc[3] += qv * bf2f(k0[n + 12288]);
  }
  float* dst = Gp + ((size_t)((s * 8 + b) * 8 + h) * 1024 + j * 32 + e0);
  #pragma unroll
  for(int i = 0; i < 4; i++) dst[i] = acc[i];
}

// ---------------------------------------------------------------------------
// K5b: attn[b][h][j][e] = softmax_e( (sum_s Gp) * invq[j] * invk[e] * temp[h] )
// ---------------------------------------------------------------------------
__global__ void k_softmax_ca(const float* __restrict__ Gp,
                             const float* __restrict__ invq,
                             const float* __restrict__ invk,
                             const float* __restrict__ temp,
                             float* __restrict__ attn){
  const int j = threadIdx.x, h = blockIdx.x, b = blockIdx.y;
  const float tm = temp[h];
  const float iq = invq[b * 256 + h * 32 + j];
  float v[32];
  float m = -1e30f;
  #pragma unroll
  for(int e = 0; e < 32; e++){
    float g = 0.f;
    #pragma unroll
    for(int s = 0; s < 8; s++)
      g += Gp[(size_t)s * 65536 + (size_t)(b * 8 + h) * 1024 + j * 32 + e];
    float val = g * iq * invk[b * 256 + h * 32 + e] * tm;
    v[e] = val; m = fmaxf(m, val);
  }
  float sum = 0.f;
  #pragma unroll
  for(int e = 0; e < 32; e++){ v[e] = __expf(v[e] - m); sum += v[e]; }
  const float inv = 1.0f / sum;
  #pragma unroll
  for(int e = 0; e < 32; e++) attn[(size_t)(b * 8 + h) * 1024 + j * 32 + e] = v[e] * inv;
}

// ---------------------------------------------------------------------------
// K6: spatial attention -> xsa[b][h][j][n] (bf16, natural layout).
// ---------------------------------------------------------------------------
__global__ __launch_bounds__(256) void k_sa8(const u16* __restrict__ q_sa,
                                             const float* __restrict__ kvp,
                                             const float* __restrict__ inv_sa,
                                             const float* __restrict__ temp2,
                                             u16* __restrict__ xsa){
  __shared__ float kp[2048];
  __shared__ float vp[2048];
  __shared__ float invl[32];
  const int t = threadIdx.x;
  const int ntile = blockIdx.x, h = blockIdx.y, b = blockIdx.z;
  {
    const float* ks = kvp + (size_t)(b * 512 + h * 32) * 64;        // k rows
    const float* vs = kvp + (size_t)(b * 512 + 256 + h * 32) * 64;  // v rows
    #pragma unroll
    for(int i = 0; i < 8; i++){
      kp[i * 256 + t] = ks[i * 256 + t];
      vp[i * 256 + t] = vs[i * 256 + t];
    }
    if(t < 32) invl[t] = inv_sa[b * 256 + h * 32 + t];
  }
  __syncthreads();
  const int n = ntile * 256 + t;
  float l[64];
  #pragma unroll
  for(int p = 0; p < 64; p++) l[p] = 0.f;
  for(int j = 0; j < 32; j++){
    const float qv = bf2f(q_sa[(size_t)(b * 256 + h * 32 + j) * 4096 + n]) * invl[j];
    const float4* k4 = (const float4*)&kp[j * 64];
    #pragma unroll
    for(int p4 = 0; p4 < 16; p4++){
      const float4 kv = k4[p4];
      l[p4*4+0] += qv*kv.x; l[p4*4+1] += qv*kv.y; l[p4*4+2] += qv*kv.z; l[p4*4+3] += qv*kv.w;
    }
  }
  const float tm = temp2[h];
  float m = -1e30f;
  #pragma unroll
  for(int p = 0; p < 64; p++){ l[p] *= tm; m = fmaxf(m, l[p]); }
  float sum = 0.f;
  #pragma unroll
  for(int p = 0; p < 64; p++){ l[p] = __expf(l[p] - m); sum += l[p]; }
  const float sinv = 1.0f / sum;
  for(int j = 0; j < 32; j++){
    const float4* v4 = (const float4*)&vp[j * 64];
    float s = 0.f;
    #pragma unroll
    for(int p4 = 0; p4 < 16; p4++){
      const float4 vv = v4[p4];
      s += l[p4*4+0]*vv.x + l[p4*4+1]*vv.y + l[p4*4+2]*vv.z + l[p4*4+3]*vv.w;
    }
    xsa[((size_t)(b * 8 + h) * 32 + j) * 4096 + n] = f2bf(s * sinv);
  }
}

// ---------------------------------------------------------------------------
// K7: sole writer of out (FP32!).
//   CA (natural): h_c=cc>>5, j_c=cc&31: sum_e attn[b,h_c,j_c,e]*Vc[b,512+h_c*32+e,nn]
//   SA (text scramble): j=nn>>7, hh=(nn>>4)&7, nh=nn&15: + xsa[b, hh, j, nh*256+cc]
// ---------------------------------------------------------------------------
__global__ __launch_bounds__(256) void k_out(const u16* __restrict__ y_sc,
                                             const float* __restrict__ attn,
                                             const u16* __restrict__ xsa,
                                             float* __restrict__ out){
  __shared__ float ar[32];
  const int t = threadIdx.x;
  const int cc = blockIdx.x, b = blockIdx.y;
  const int h_c = cc >> 5, j_c = cc & 31;
  if(t < 32) ar[t] = attn[(size_t)(b * 8 + h_c) * 1024 + j_c * 32 + t];
  __syncthreads();
  const u16* vc = y_sc + (size_t)(b * 768 + 512 + h_c * 32) * 4096;
  for(int i = 0; i < 16; i++){
    const int nn = i * 256 + t;
    const int j = nn >> 7, hh = (nn >> 4) & 7, nh = nn & 15;
    const float sa = bf2f(xsa[((size_t)(b * 8 + hh) * 32 + j) * 4096 + nh * 256 + cc]);
    float s = 0.f;
    #pragma unroll
    for(int e = 0; e < 32; e++)
      s += ar[e] * bf2f(vc[(size_t)e * 4096 + nn]);
    out[(size_t)(b * 256 + cc) * 4096 + nn] = s + sa;
  }
}

// ---------------------------------------------------------------------------
// Workspace layout (bytes), total ~91.0 MB (xsa overlays dead xb).
// ---------------------------------------------------------------------------
#define OFF_XB    ((size_t)0)           // u16 [8][256][4096] 16,777,216 (reused as xsa)
#define OFF_QSA   ((size_t)16777216)    // u16 [8][256][4096] 16,777,216
#define OFF_YSC   ((size_t)33554432)    // u16 [8][768][4096] 50,331,648
#define OFF_WSAF  ((size_t)83886080)    // f32 [1024][256]     1,048,576
#define OFF_WSCF  ((size_t)84934656)    // f32 [1024][256]     1,048,576
#define OFF_EFF   ((size_t)85983232)    // f32 [4096][64]      1,048,576
#define OFF_XEF   ((size_t)87031808)    // f32 [8][256][64]      524,288
#define OFF_KVP   ((size_t)87556096)    // f32 [8][512][64]    1,048,576
#define OFF_ISA   ((size_t)88604672)    // f32 [8][256]            8,192
#define OFF_IQC   ((size_t)88612864)
#define OFF_IKC   ((size_t)88621056)
#define OFF_GP    ((size_t)88629248)    // f32 [8][8][8][32][32] 2,097,152
#define OFF_ATT   ((size_t)90726400)    // f32 [8][8][32][32]    262,144
#define OFF_TF    ((size_t)90988544)    // f32 [16]
#define OFF_FLAG  ((size_t)90988608)    // u32

extern "C" void kernel_launch(void* const* d_in, const int* in_sizes, int n_in,
                              void* d_out, int out_size, void* d_ws, size_t ws_size,
                              hipStream_t stream){
  (void)in_sizes; (void)n_in; (void)out_size; (void)ws_size;
  char* ws = (char*)d_ws;
  u16*   xb    = (u16*)  (ws + OFF_XB);
  u16*   xsa   = (u16*)  (ws + OFF_XB);    // overlay: xb dead after k_gemm4/k_xef4
  u16*   q_sa  = (u16*)  (ws + OFF_QSA);
  u16*   y_sc  = (u16*)  (ws + OFF_YSC);
  float* Wsaf  = (float*)(ws + OFF_WSAF);
  float* Wscf  = (float*)(ws + OFF_WSCF);
  float* EFf   = (float*)(ws + OFF_EFF);
  float* xef   = (float*)(ws + OFF_XEF);
  float* kvp   = (float*)(ws + OFF_KVP);
  float* invsa = (float*)(ws + OFF_ISA);
  float* invqc = (float*)(ws + OFF_IQC);
  float* invkc = (float*)(ws + OFF_IKC);
  float* Gp    = (float*)(ws + OFF_GP);
  float* attn  = (float*)(ws + OFF_ATT);
  float* tf    = (float*)(ws + OFF_TF);
  u32*   flag  = (u32*)  (ws + OFF_FLAG);
  float* out = (float*)d_out;   // FP32 output per reference dtype

  // dtype detect + canonicalize
  k_detect<<<1, 256, 0, stream>>>((const u16*)d_in[0], flag);
  k_conv_bf <<<4096, 256, 0, stream>>>(d_in[0], xb, 8388608, flag);   // x -> bf16
  k_conv_f32<<<256,  256, 0, stream>>>(d_in[1], Wsaf, 262144, flag);  // W_sa -> f32
  k_conv_f32<<<256,  256, 0, stream>>>(d_in[2], EFf,  262144, flag);  // EF -> f32
  k_conv_f32<<<256,  256, 0, stream>>>(d_in[4], Wscf, 262144, flag);  // W_sc -> f32
  k_conv_f32<<<1,    256, 0, stream>>>(d_in[3], tf,        8, flag);  // temp2_sa
  k_conv_f32<<<1,    256, 0, stream>>>(d_in[5], tf + 8,    8, flag);  // temp_sc

  // QKV GEMMs
  k_gemm4<<<dim3(64, 8),  256, 0, stream>>>(Wsaf, xb, q_sa, 256);
  k_gemm4<<<dim3(192, 8), 256, 0, stream>>>(Wscf, xb, y_sc, 768);
  // Linformer projection via associativity: xef = x @ EF, then kvp = W_kv @ xef
  k_xef4<<<dim3(64, 8),  256, 0, stream>>>(xb, EFf, xef);
  k_kv4 <<<dim3(128, 8), 256, 0, stream>>>(Wsaf, xef, kvp);
  // L2 norms (reciprocals)
  k_norm<<<dim3(256, 8), 256, 0, stream>>>(q_sa, invsa, 256, 0);
  k_norm<<<dim3(256, 8), 256, 0, stream>>>(y_sc, invqc, 768, 0);
  k_norm<<<dim3(256, 8), 256, 0, stream>>>(y_sc, invkc, 768, 256);
  // Channel attention matrix
  k_gram8<<<dim3(8, 8, 8), 256, 0, stream>>>(y_sc, Gp);
  k_softmax_ca<<<dim3(8, 8), 32, 0, stream>>>(Gp, invqc, invkc, tf + 8, attn);
  // Spatial attention -> xsa (natural layout), then scramble-gather -> fp32 out
  k_sa8<<<dim3(16, 8, 8), 256, 0, stream>>>(q_sa, kvp, invsa, tf, xsa);
  k_out<<<dim3(256, 8), 256, 0, stream>>>(y_sc, attn, xsa, out);
}

// Round 8
// 695.642 us; speedup vs baseline: 1.2361x; 1.2361x over previous
//
#include <hip/hip_runtime.h>

typedef unsigned short u16;
typedef unsigned int   u32;

typedef __attribute__((ext_vector_type(4))) short short4v;
typedef __attribute__((ext_vector_type(8))) short bf16x8;  // 8 bf16 (4 VGPRs)
typedef __attribute__((ext_vector_type(4))) float f32x4;

// Problem: B=8, C=256, N=4096, heads=8, d=32, P=64. Inputs fp32 (auto-detect),
// output FP32. Passing r7 pipeline; this round: MFMA bf16 GEMM replaces k_gemm4.

__device__ __forceinline__ float bf2f(u16 u){
  union { u32 i; float f; } v; v.i = ((u32)u) << 16; return v.f;
}
__device__ __forceinline__ u16 f2bf(float f){
  u32 u = __float_as_uint(f);
  u32 r = u + 0x7FFFu + ((u >> 16) & 1u);   // RNE
  return (u16)(r >> 16);
}

// ---------------------------------------------------------------------------
// K0a: dtype detector on x. flag=1 => fp32 input.
// ---------------------------------------------------------------------------
__global__ void k_detect(const u16* __restrict__ x, u32* __restrict__ flag){
  __shared__ int cnt[256];
  const int t = threadIdx.x;
  int c = 0;
  #pragma unroll
  for(int i = 0; i < 4; i++){
    u16 v = x[t * 4 + i];
    int e = (v >> 7) & 0xFF;
    if(e >= 112 && e <= 134) c++;
  }
  cnt[t] = c;
  __syncthreads();
  for(int s = 128; s > 0; s >>= 1){
    if(t < s) cnt[t] += cnt[t + s];
    __syncthreads();
  }
  if(t == 0) *flag = (cnt[0] < 800) ? 1u : 0u;
}

// ---------------------------------------------------------------------------
// K0b: canonicalize to bf16 (8 elems/thread).
// ---------------------------------------------------------------------------
__global__ __launch_bounds__(256) void k_conv_bf(const void* __restrict__ src,
                                                 u16* __restrict__ dst, int n,
                                                 const u32* __restrict__ flag){
  const int i0 = (blockIdx.x * 256 + threadIdx.x) * 8;
  if(i0 >= n) return;
  const bool isf32 = (*flag != 0);
  if(isf32){
    const float4 a = *(const float4*)((const float*)src + i0);
    const float4 b = *(const float4*)((const float*)src + i0 + 4);
    uint4 o;
    o.x = (u32)f2bf(a.x) | ((u32)f2bf(a.y) << 16);
    o.y = (u32)f2bf(a.z) | ((u32)f2bf(a.w) << 16);
    o.z = (u32)f2bf(b.x) | ((u32)f2bf(b.y) << 16);
    o.w = (u32)f2bf(b.z) | ((u32)f2bf(b.w) << 16);
    *(uint4*)(dst + i0) = o;
  } else {
    *(uint4*)(dst + i0) = *(const uint4*)((const u16*)src + i0);
  }
}

// ---------------------------------------------------------------------------
// K0c: canonicalize to fp32 (4 elems/thread).
// ---------------------------------------------------------------------------
__global__ __launch_bounds__(256) void k_conv_f32(const void* __restrict__ src,
                                                  float* __restrict__ dst, int n,
                                                  const u32* __restrict__ flag){
  const int i0 = (blockIdx.x * 256 + threadIdx.x) * 4;
  if(i0 >= n) return;
  const bool isf32 = (*flag != 0);
  if(isf32){
    *(float4*)(dst + i0) = *(const float4*)((const float*)src + i0);
  } else {
    const uint2 a = *(const uint2*)((const u16*)src + i0);
    float4 o;
    o.x = bf2f((u16)(a.x & 0xFFFF)); o.y = bf2f((u16)(a.x >> 16));
    o.z = bf2f((u16)(a.y & 0xFFFF)); o.w = bf2f((u16)(a.y >> 16));
    *(float4*)(dst + i0) = o;
  }
}

// ---------------------------------------------------------------------------
// K0d: canonicalize to BOTH fp32 and bf16 (4 elems/thread) — for W_sa.
// ---------------------------------------------------------------------------
__global__ __launch_bounds__(256) void k_conv_both(const void* __restrict__ src,
                                                   float* __restrict__ dstf,
                                                   u16* __restrict__ dstb, int n,
                                                   const u32* __restrict__ flag){
  const int i0 = (blockIdx.x * 256 + threadIdx.x) * 4;
  if(i0 >= n) return;
  const bool isf32 = (*flag != 0);
  float4 o;
  if(isf32){
    o = *(const float4*)((const float*)src + i0);
  } else {
    const uint2 a = *(const uint2*)((const u16*)src + i0);
    o.x = bf2f((u16)(a.x & 0xFFFF)); o.y = bf2f((u16)(a.x >> 16));
    o.z = bf2f((u16)(a.y & 0xFFFF)); o.w = bf2f((u16)(a.y >> 16));
  }
  *(float4*)(dstf + i0) = o;
  uint2 pk;
  pk.x = (u32)f2bf(o.x) | ((u32)f2bf(o.y) << 16);
  pk.y = (u32)f2bf(o.z) | ((u32)f2bf(o.w) << 16);
  *(uint2*)(dstb + i0) = pk;
}

// ---------------------------------------------------------------------------
// K1: MFMA GEMM. Y[b, m, n] = sum_c W[m,c] * x[b,c,n]  (bf16 in, bf16 out).
// Role-swapped: D[n][m] = sum_k A[n][k] * B[k][m], A = x^T (LDS-transposed
// staging), B = W (natural k-contiguous). Tile 64n x 64m, K-chunks of 64,
// 4 waves (wave w: n-rows w*16..w*16+16, all 64 m as 4 subtiles).
// mfma_f32_16x16x32_bf16 layouts (HW-verified per guide):
//   a-frag: lane l -> A[n=l&15][k=(l>>4)*8+j]
//   b-frag: lane l -> B[k=(l>>4)*8+j][m=l&15]
//   d:      lane l -> D[n=(l>>4)*4+reg][m=l&15]
// ---------------------------------------------------------------------------
__device__ __forceinline__ bf16x8 ld_frag8(const u16* p){  // 8 contig bf16, 8B-aligned
  short4v lo = *(const short4v*)p;
  short4v hi = *(const short4v*)(p + 4);
  bf16x8 r;
  r[0]=lo[0]; r[1]=lo[1]; r[2]=lo[2]; r[3]=lo[3];
  r[4]=hi[0]; r[5]=hi[1]; r[6]=hi[2]; r[7]=hi[3];
  return r;
}

__global__ __launch_bounds__(256) void k_gemm_mfma(const u16* __restrict__ Wb,
                                                   const u16* __restrict__ xb,
                                                   u16* __restrict__ Y,
                                                   int rows_per_b){
  __shared__ u16 As[64][68];    // [n][k] — transposed x tile (pitch 68: 2-ish-way)
  __shared__ u16 Ws[64][68];    // [m][k] — natural W tile
  __shared__ float Cs[64][69];  // [m][n] epilogue transpose (pitch 69)
  const int t = threadIdx.x;
  const int n0 = blockIdx.x * 64, m0 = blockIdx.y * 64, b = blockIdx.z;
  const int lane = t & 63, w = t >> 6;
  const int fm = lane & 15, fq = lane >> 4;
  f32x4 acc[4] = {};
  for(int kc = 0; kc < 256; kc += 64){
    // --- stage A transposed: x[b][kc+cl][n0+ns..+8] -> As[ns+i][cl]
    #pragma unroll
    for(int half = 0; half < 2; half++){
      const int cl = half * 32 + (t >> 3);
      const int ns = (t & 7) * 8;
      const u16* sx = xb + (size_t)(b * 256 + kc + cl) * 4096 + n0 + ns;
      uint4 xv = *(const uint4*)sx;
      u16 e[8]; *(uint4*)e = xv;
      #pragma unroll
      for(int i = 0; i < 8; i++) As[ns + i][cl] = e[i];
    }
    // --- stage W natural: W[m0+r][kc+seg..+16] -> Ws[r][seg..]
    {
      const int r = t >> 2, seg = (t & 3) * 16;
      const u16* sw = Wb + (size_t)(m0 + r) * 256 + kc + seg;
      uint2 w0 = *(const uint2*)sw;
      uint2 w1 = *(const uint2*)(sw + 4);
      uint2 w2 = *(const uint2*)(sw + 8);
      uint2 w3 = *(const uint2*)(sw + 12);
      *(uint2*)&Ws[r][seg]      = w0;
      *(uint2*)&Ws[r][seg + 4]  = w1;
      *(uint2*)&Ws[r][seg + 8]  = w2;
      *(uint2*)&Ws[r][seg + 12] = w3;
    }
    __syncthreads();
    #pragma unroll
    for(int ks = 0; ks < 2; ks++){
      const int kb = ks * 32 + fq * 8;
      bf16x8 a = ld_frag8(&As[w * 16 + fm][kb]);
      #pragma unroll
      for(int nt = 0; nt < 4; nt++){
        bf16x8 bb = ld_frag8(&Ws[nt * 16 + fm][kb]);
        acc[nt] = __builtin_amdgcn_mfma_f32_16x16x32_bf16(a, bb, acc[nt], 0, 0, 0);
      }
    }
    __syncthreads();
  }
  // epilogue: D[n = w*16 + fq*4 + reg][m = nt*16 + fm] -> Cs[m][n] -> coalesced store
  #pragma unroll
  for(int nt = 0; nt < 4; nt++){
    #pragma unroll
    for(int r = 0; r < 4; r++)
      Cs[nt * 16 + fm][w * 16 + fq * 4 + r] = acc[nt][r];
  }
  __syncthreads();
  {
    const int r = t >> 2, seg = (t & 3) * 16;
    uint4 o0, o1;
    u32 pk[8];
    #pragma unroll
    for(int i = 0; i < 8; i++)
      pk[i] = (u32)f2bf(Cs[r][seg + 2*i]) | ((u32)f2bf(Cs[r][seg + 2*i + 1]) << 16);
    o0.x = pk[0]; o0.y = pk[1]; o0.z = pk[2]; o0.w = pk[3];
    o1.x = pk[4]; o1.y = pk[5]; o1.z = pk[6]; o1.w = pk[7];
    u16* yp = Y + (size_t)(b * rows_per_b + m0 + r) * 4096 + n0 + seg;
    *(uint4*)yp = o0;
    *(uint4*)(yp + 8) = o1;
  }
}

// ---------------------------------------------------------------------------
// K2: xef[b,c,p] = sum_n xb[b,c,n] * EFf[n,p].  Block: 4 c x 64 p.
// ---------------------------------------------------------------------------
__global__ __launch_bounds__(256) void k_xef4(const u16* __restrict__ xb,
                                              const float* __restrict__ EFf,
                                              float* __restrict__ xef){
  const int t = threadIdx.x;
  const int ci = t >> 6, p = t & 63;
  const int c = blockIdx.x * 4 + ci, b = blockIdx.y;
  const u16* xr = xb + (size_t)(b * 256 + c) * 4096;
  float acc = 0.f;
  for(int n = 0; n < 4096; n++)
    acc += bf2f(xr[n]) * EFf[(size_t)n * 64 + p];
  xef[(size_t)(b * 256 + c) * 64 + p] = acc;
}

// ---------------------------------------------------------------------------
// K3: kvp[b, r, p] = sum_c W_sa[row_w(r), c] * xef[b, c, p]
// r in [0,256): k rows (W_sa 256:512); r in [256,512): v rows (W_sa 768:1024).
// ---------------------------------------------------------------------------
__global__ __launch_bounds__(256) void k_kv4(const float* __restrict__ Wsaf,
                                             const float* __restrict__ xef,
                                             float* __restrict__ kvp){
  const int t = threadIdx.x;
  const int ri = t >> 6, p = t & 63;
  const int r = blockIdx.x * 4 + ri, b = blockIdx.y;
  const int row_w = (r < 256) ? (256 + r) : (512 + r);
  const float* wr = Wsaf + (size_t)row_w * 256;
  const float* xr = xef + (size_t)(b * 256) * 64 + p;
  float acc = 0.f;
  for(int c = 0; c < 256; c++)
    acc += wr[c] * xr[(size_t)c * 64];
  kvp[(size_t)(b * 512 + r) * 64 + p] = acc;
}

// ---------------------------------------------------------------------------
// K4: dst[b*256+r] = 1 / max(||row||_2, 1e-12), LDS tree reduction.
// ---------------------------------------------------------------------------
__global__ __launch_bounds__(256) void k_norm(const u16* __restrict__ src,
                                              float* __restrict__ dst,
                                              int stride_b, int row_off){
  __shared__ float red[256];
  const int r = blockIdx.x, b = blockIdx.y, t = threadIdx.x;
  const u16* row = src + (size_t)(b * stride_b + row_off + r) * 4096;
  float s = 0.f;
  #pragma unroll
  for(int i = 0; i < 16; i++){ float v = bf2f(row[t + 256 * i]); s += v * v; }
  red[t] = s;
  __syncthreads();
  for(int s2 = 128; s2 > 0; s2 >>= 1){
    if(t < s2) red[t] += red[t + s2];
    __syncthreads();
  }
  if(t == 0) dst[b * 256 + r] = 1.0f / fmaxf(sqrtf(red[0]), 1e-12f);
}

// ---------------------------------------------------------------------------
// K5: Gram partials over n-split s: Gp[s][b][h][j][e] = sum_n qc[j,n]*kc[e,n].
// ---------------------------------------------------------------------------
__global__ __launch_bounds__(256) void k_gram8(const u16* __restrict__ y_sc,
                                               float* __restrict__ Gp){
  const int t = threadIdx.x;
  const int s = blockIdx.x, h = blockIdx.y, b = blockIdx.z;
  const int j = t >> 3, e0 = (t & 7) * 4;
  const u16* qr = y_sc + (size_t)(b * 768 + h * 32 + j) * 4096;
  const u16* k0 = y_sc + (size_t)(b * 768 + 256 + h * 32 + e0) * 4096;
  float acc[4] = {};
  for(int n = s * 512; n < s * 512 + 512; n++){
    const float qv = bf2f(qr[n]);
    acc[0] += qv * bf2f(k0[n]);
    acc[1] += qv * bf2f(k0[n + 4096]);
    acc[2] += qv * bf2f(k0[n + 8192]);
    acc[3] += qv * bf2f(k0[n + 12288]);
  }
  float* dst = Gp + ((size_t)((s * 8 + b) * 8 + h) * 1024 + j * 32 + e0);
  #pragma unroll
  for(int i = 0; i < 4; i++) dst[i] = acc[i];
}

// ---------------------------------------------------------------------------
// K5b: attn[b][h][j][e] = softmax_e( (sum_s Gp) * invq[j] * invk[e] * temp[h] )
// ---------------------------------------------------------------------------
__global__ void k_softmax_ca(const float* __restrict__ Gp,
                             const float* __restrict__ invq,
                             const float* __restrict__ invk,
                             const float* __restrict__ temp,
                             float* __restrict__ attn){
  const int j = threadIdx.x, h = blockIdx.x, b = blockIdx.y;
  const float tm = temp[h];
  const float iq = invq[b * 256 + h * 32 + j];
  float v[32];
  float m = -1e30f;
  #pragma unroll
  for(int e = 0; e < 32; e++){
    float g = 0.f;
    #pragma unroll
    for(int s = 0; s < 8; s++)
      g += Gp[(size_t)s * 65536 + (size_t)(b * 8 + h) * 1024 + j * 32 + e];
    float val = g * iq * invk[b * 256 + h * 32 + e] * tm;
    v[e] = val; m = fmaxf(m, val);
  }
  float sum = 0.f;
  #pragma unroll
  for(int e = 0; e < 32; e++){ v[e] = __expf(v[e] - m); sum += v[e]; }
  const float inv = 1.0f / sum;
  #pragma unroll
  for(int e = 0; e < 32; e++) attn[(size_t)(b * 8 + h) * 1024 + j * 32 + e] = v[e] * inv;
}

// ---------------------------------------------------------------------------
// K6: spatial attention -> xsa[b][h][j][n] (bf16, natural layout).
// ---------------------------------------------------------------------------
__global__ __launch_bounds__(256) void k_sa8(const u16* __restrict__ q_sa,
                                             const float* __restrict__ kvp,
                                             const float* __restrict__ inv_sa,
                                             const float* __restrict__ temp2,
                                             u16* __restrict__ xsa){
  __shared__ float kp[2048];
  __shared__ float vp[2048];
  __shared__ float invl[32];
  const int t = threadIdx.x;
  const int ntile = blockIdx.x, h = blockIdx.y, b = blockIdx.z;
  {
    const float* ks = kvp + (size_t)(b * 512 + h * 32) * 64;        // k rows
    const float* vs = kvp + (size_t)(b * 512 + 256 + h * 32) * 64;  // v rows
    #pragma unroll
    for(int i = 0; i < 8; i++){
      kp[i * 256 + t] = ks[i * 256 + t];
      vp[i * 256 + t] = vs[i * 256 + t];
    }
    if(t < 32) invl[t] = inv_sa[b * 256 + h * 32 + t];
  }
  __syncthreads();
  const int n = ntile * 256 + t;
  float l[64];
  #pragma unroll
  for(int p = 0; p < 64; p++) l[p] = 0.f;
  for(int j = 0; j < 32; j++){
    const float qv = bf2f(q_sa[(size_t)(b * 256 + h * 32 + j) * 4096 + n]) * invl[j];
    const float4* k4 = (const float4*)&kp[j * 64];
    #pragma unroll
    for(int p4 = 0; p4 < 16; p4++){
      const float4 kv = k4[p4];
      l[p4*4+0] += qv*kv.x; l[p4*4+1] += qv*kv.y; l[p4*4+2] += qv*kv.z; l[p4*4+3] += qv*kv.w;
    }
  }
  const float tm = temp2[h];
  float m = -1e30f;
  #pragma unroll
  for(int p = 0; p < 64; p++){ l[p] *= tm; m = fmaxf(m, l[p]); }
  float sum = 0.f;
  #pragma unroll
  for(int p = 0; p < 64; p++){ l[p] = __expf(l[p] - m); sum += l[p]; }
  const float sinv = 1.0f / sum;
  for(int j = 0; j < 32; j++){
    const float4* v4 = (const float4*)&vp[j * 64];
    float s = 0.f;
    #pragma unroll
    for(int p4 = 0; p4 < 16; p4++){
      const float4 vv = v4[p4];
      s += l[p4*4+0]*vv.x + l[p4*4+1]*vv.y + l[p4*4+2]*vv.z + l[p4*4+3]*vv.w;
    }
    xsa[((size_t)(b * 8 + h) * 32 + j) * 4096 + n] = f2bf(s * sinv);
  }
}

// ---------------------------------------------------------------------------
// K7: sole writer of out (FP32).
//   CA (natural): h_c=cc>>5, j_c=cc&31: sum_e attn[b,h_c,j_c,e]*Vc[b,512+h_c*32+e,nn]
//   SA (text scramble): j=nn>>7, hh=(nn>>4)&7, nh=nn&15: + xsa[b, hh, j, nh*256+cc]
// ---------------------------------------------------------------------------
__global__ __launch_bounds__(256) void k_out(const u16* __restrict__ y_sc,
                                             const float* __restrict__ attn,
                                             const u16* __restrict__ xsa,
                                             float* __restrict__ out){
  __shared__ float ar[32];
  const int t = threadIdx.x;
  const int cc = blockIdx.x, b = blockIdx.y;
  const int h_c = cc >> 5, j_c = cc & 31;
  if(t < 32) ar[t] = attn[(size_t)(b * 8 + h_c) * 1024 + j_c * 32 + t];
  __syncthreads();
  const u16* vc = y_sc + (size_t)(b * 768 + 512 + h_c * 32) * 4096;
  for(int i = 0; i < 16; i++){
    const int nn = i * 256 + t;
    const int j = nn >> 7, hh = (nn >> 4) & 7, nh = nn & 15;
    const float sa = bf2f(xsa[((size_t)(b * 8 + hh) * 32 + j) * 4096 + nh * 256 + cc]);
    float s = 0.f;
    #pragma unroll
    for(int e = 0; e < 32; e++)
      s += ar[e] * bf2f(vc[(size_t)e * 4096 + nn]);
    out[(size_t)(b * 256 + cc) * 4096 + nn] = s + sa;
  }
}

// ---------------------------------------------------------------------------
// Workspace layout (bytes), total ~91.0 MB (unchanged from r7).
// WSCF region (fp32 W_sc, no longer needed) reused for bf16 weight copies.
// ---------------------------------------------------------------------------
#define OFF_XB    ((size_t)0)           // u16 [8][256][4096] 16,777,216 (reused as xsa)
#define OFF_QSA   ((size_t)16777216)    // u16 [8][256][4096] 16,777,216
#define OFF_YSC   ((size_t)33554432)    // u16 [8][768][4096] 50,331,648
#define OFF_WSAF  ((size_t)83886080)    // f32 [1024][256]     1,048,576
#define OFF_WBSA  ((size_t)84934656)    // u16 [1024][256]       524,288 (bf16 W_sa)
#define OFF_WBSC  ((size_t)85458944)    // u16 [1024][256]       524,288 (bf16 W_sc, rows 0:768 used)
#define OFF_EFF   ((size_t)85983232)    // f32 [4096][64]      1,048,576
#define OFF_XEF   ((size_t)87031808)    // f32 [8][256][64]      524,288
#define OFF_KVP   ((size_t)87556096)    // f32 [8][512][64]    1,048,576
#define OFF_ISA   ((size_t)88604672)    // f32 [8][256]            8,192
#define OFF_IQC   ((size_t)88612864)
#define OFF_IKC   ((size_t)88621056)
#define OFF_GP    ((size_t)88629248)    // f32 [8][8][8][32][32] 2,097,152
#define OFF_ATT   ((size_t)90726400)    // f32 [8][8][32][32]    262,144
#define OFF_TF    ((size_t)90988544)    // f32 [16]
#define OFF_FLAG  ((size_t)90988608)    // u32

extern "C" void kernel_launch(void* const* d_in, const int* in_sizes, int n_in,
                              void* d_out, int out_size, void* d_ws, size_t ws_size,
                              hipStream_t stream){
  (void)in_sizes; (void)n_in; (void)out_size; (void)ws_size;
  char* ws = (char*)d_ws;
  u16*   xb    = (u16*)  (ws + OFF_XB);
  u16*   xsa   = (u16*)  (ws + OFF_XB);    // overlay: xb dead after gemms/xef4
  u16*   q_sa  = (u16*)  (ws + OFF_QSA);
  u16*   y_sc  = (u16*)  (ws + OFF_YSC);
  float* Wsaf  = (float*)(ws + OFF_WSAF);
  u16*   WbSA  = (u16*)  (ws + OFF_WBSA);
  u16*   WbSC  = (u16*)  (ws + OFF_WBSC);
  float* EFf   = (float*)(ws + OFF_EFF);
  float* xef   = (float*)(ws + OFF_XEF);
  float* kvp   = (float*)(ws + OFF_KVP);
  float* invsa = (float*)(ws + OFF_ISA);
  float* invqc = (float*)(ws + OFF_IQC);
  float* invkc = (float*)(ws + OFF_IKC);
  float* Gp    = (float*)(ws + OFF_GP);
  float* attn  = (float*)(ws + OFF_ATT);
  float* tf    = (float*)(ws + OFF_TF);
  u32*   flag  = (u32*)  (ws + OFF_FLAG);
  float* out = (float*)d_out;

  // dtype detect + canonicalize
  k_detect<<<1, 256, 0, stream>>>((const u16*)d_in[0], flag);
  k_conv_bf  <<<4096, 256, 0, stream>>>(d_in[0], xb, 8388608, flag);          // x -> bf16
  k_conv_both<<<256,  256, 0, stream>>>(d_in[1], Wsaf, WbSA, 262144, flag);   // W_sa -> f32+bf16
  k_conv_f32 <<<256,  256, 0, stream>>>(d_in[2], EFf, 262144, flag);          // EF -> f32
  k_conv_bf  <<<128,  256, 0, stream>>>(d_in[4], WbSC, 262144, flag);         // W_sc -> bf16
  k_conv_f32 <<<1,    256, 0, stream>>>(d_in[3], tf,      8, flag);           // temp2_sa
  k_conv_f32 <<<1,    256, 0, stream>>>(d_in[5], tf + 8,  8, flag);           // temp_sc

  // QKV GEMMs (MFMA)
  k_gemm_mfma<<<dim3(64, 4, 8),  256, 0, stream>>>(WbSA, xb, q_sa, 256);
  k_gemm_mfma<<<dim3(64, 12, 8), 256, 0, stream>>>(WbSC, xb, y_sc, 768);
  // Linformer projection via associativity: xef = x @ EF, then kvp = W_kv @ xef
  k_xef4<<<dim3(64, 8),  256, 0, stream>>>(xb, EFf, xef);
  k_kv4 <<<dim3(128, 8), 256, 0, stream>>>(Wsaf, xef, kvp);
  // L2 norms (reciprocals)
  k_norm<<<dim3(256, 8), 256, 0, stream>>>(q_sa, invsa, 256, 0);
  k_norm<<<dim3(256, 8), 256, 0, stream>>>(y_sc, invqc, 768, 0);
  k_norm<<<dim3(256, 8), 256, 0, stream>>>(y_sc, invkc, 768, 256);
  // Channel attention matrix
  k_gram8<<<dim3(8, 8, 8), 256, 0, stream>>>(y_sc, Gp);
  k_softmax_ca<<<dim3(8, 8), 32, 0, stream>>>(Gp, invqc, invkc, tf + 8, attn);
  // Spatial attention -> xsa (natural layout), then scramble-gather -> fp32 out
  k_sa8<<<dim3(16, 8, 8), 256, 0, stream>>>(q_sa, kvp, invsa, tf, xsa);
  k_out<<<dim3(256, 8), 256, 0, stream>>>(y_sc, attn, xsa, out);
}

// Round 9
// 547.976 us; speedup vs baseline: 1.5692x; 1.2695x over previous
//
#include <hip/hip_runtime.h>

typedef unsigned short u16;
typedef unsigned int   u32;

typedef __attribute__((ext_vector_type(4))) short short4v;
typedef __attribute__((ext_vector_type(8))) short bf16x8;  // 8 bf16 (4 VGPRs)
typedef __attribute__((ext_vector_type(4))) float f32x4;

// Problem: B=8, C=256, N=4096, heads=8, d=32, P=64. Inputs fp32 (auto-detect),
// output FP32. r8: MFMA GEMMs. r9: tiled k_out2 (LDS-staged scramble-gather).

__device__ __forceinline__ float bf2f(u16 u){
  union { u32 i; float f; } v; v.i = ((u32)u) << 16; return v.f;
}
__device__ __forceinline__ u16 f2bf(float f){
  u32 u = __float_as_uint(f);
  u32 r = u + 0x7FFFu + ((u >> 16) & 1u);   // RNE
  return (u16)(r >> 16);
}

// ---------------------------------------------------------------------------
// K0a: dtype detector on x. flag=1 => fp32 input.
// ---------------------------------------------------------------------------
__global__ void k_detect(const u16* __restrict__ x, u32* __restrict__ flag){
  __shared__ int cnt[256];
  const int t = threadIdx.x;
  int c = 0;
  #pragma unroll
  for(int i = 0; i < 4; i++){
    u16 v = x[t * 4 + i];
    int e = (v >> 7) & 0xFF;
    if(e >= 112 && e <= 134) c++;
  }
  cnt[t] = c;
  __syncthreads();
  for(int s = 128; s > 0; s >>= 1){
    if(t < s) cnt[t] += cnt[t + s];
    __syncthreads();
  }
  if(t == 0) *flag = (cnt[0] < 800) ? 1u : 0u;
}

// ---------------------------------------------------------------------------
// K0b: canonicalize to bf16 (8 elems/thread).
// ---------------------------------------------------------------------------
__global__ __launch_bounds__(256) void k_conv_bf(const void* __restrict__ src,
                                                 u16* __restrict__ dst, int n,
                                                 const u32* __restrict__ flag){
  const int i0 = (blockIdx.x * 256 + threadIdx.x) * 8;
  if(i0 >= n) return;
  const bool isf32 = (*flag != 0);
  if(isf32){
    const float4 a = *(const float4*)((const float*)src + i0);
    const float4 b = *(const float4*)((const float*)src + i0 + 4);
    uint4 o;
    o.x = (u32)f2bf(a.x) | ((u32)f2bf(a.y) << 16);
    o.y = (u32)f2bf(a.z) | ((u32)f2bf(a.w) << 16);
    o.z = (u32)f2bf(b.x) | ((u32)f2bf(b.y) << 16);
    o.w = (u32)f2bf(b.z) | ((u32)f2bf(b.w) << 16);
    *(uint4*)(dst + i0) = o;
  } else {
    *(uint4*)(dst + i0) = *(const uint4*)((const u16*)src + i0);
  }
}

// ---------------------------------------------------------------------------
// K0c: canonicalize to fp32 (4 elems/thread).
// ---------------------------------------------------------------------------
__global__ __launch_bounds__(256) void k_conv_f32(const void* __restrict__ src,
                                                  float* __restrict__ dst, int n,
                                                  const u32* __restrict__ flag){
  const int i0 = (blockIdx.x * 256 + threadIdx.x) * 4;
  if(i0 >= n) return;
  const bool isf32 = (*flag != 0);
  if(isf32){
    *(float4*)(dst + i0) = *(const float4*)((const float*)src + i0);
  } else {
    const uint2 a = *(const uint2*)((const u16*)src + i0);
    float4 o;
    o.x = bf2f((u16)(a.x & 0xFFFF)); o.y = bf2f((u16)(a.x >> 16));
    o.z = bf2f((u16)(a.y & 0xFFFF)); o.w = bf2f((u16)(a.y >> 16));
    *(float4*)(dst + i0) = o;
  }
}

// ---------------------------------------------------------------------------
// K0d: canonicalize to BOTH fp32 and bf16 (4 elems/thread) — for W_sa.
// ---------------------------------------------------------------------------
__global__ __launch_bounds__(256) void k_conv_both(const void* __restrict__ src,
                                                   float* __restrict__ dstf,
                                                   u16* __restrict__ dstb, int n,
                                                   const u32* __restrict__ flag){
  const int i0 = (blockIdx.x * 256 + threadIdx.x) * 4;
  if(i0 >= n) return;
  const bool isf32 = (*flag != 0);
  float4 o;
  if(isf32){
    o = *(const float4*)((const float*)src + i0);
  } else {
    const uint2 a = *(const uint2*)((const u16*)src + i0);
    o.x = bf2f((u16)(a.x & 0xFFFF)); o.y = bf2f((u16)(a.x >> 16));
    o.z = bf2f((u16)(a.y & 0xFFFF)); o.w = bf2f((u16)(a.y >> 16));
  }
  *(float4*)(dstf + i0) = o;
  uint2 pk;
  pk.x = (u32)f2bf(o.x) | ((u32)f2bf(o.y) << 16);
  pk.y = (u32)f2bf(o.z) | ((u32)f2bf(o.w) << 16);
  *(uint2*)(dstb + i0) = pk;
}

// ---------------------------------------------------------------------------
// K1: MFMA GEMM. Y[b, m, n] = sum_c W[m,c] * x[b,c,n]  (bf16 in, bf16 out).
// Role-swapped: D[n][m] = sum_k A[n][k] * B[k][m]. (unchanged from r8)
// ---------------------------------------------------------------------------
__device__ __forceinline__ bf16x8 ld_frag8(const u16* p){
  short4v lo = *(const short4v*)p;
  short4v hi = *(const short4v*)(p + 4);
  bf16x8 r;
  r[0]=lo[0]; r[1]=lo[1]; r[2]=lo[2]; r[3]=lo[3];
  r[4]=hi[0]; r[5]=hi[1]; r[6]=hi[2]; r[7]=hi[3];
  return r;
}

__global__ __launch_bounds__(256) void k_gemm_mfma(const u16* __restrict__ Wb,
                                                   const u16* __restrict__ xb,
                                                   u16* __restrict__ Y,
                                                   int rows_per_b){
  __shared__ u16 As[64][68];
  __shared__ u16 Ws[64][68];
  __shared__ float Cs[64][69];
  const int t = threadIdx.x;
  const int n0 = blockIdx.x * 64, m0 = blockIdx.y * 64, b = blockIdx.z;
  const int lane = t & 63, w = t >> 6;
  const int fm = lane & 15, fq = lane >> 4;
  f32x4 acc[4] = {};
  for(int kc = 0; kc < 256; kc += 64){
    #pragma unroll
    for(int half = 0; half < 2; half++){
      const int cl = half * 32 + (t >> 3);
      const int ns = (t & 7) * 8;
      const u16* sx = xb + (size_t)(b * 256 + kc + cl) * 4096 + n0 + ns;
      uint4 xv = *(const uint4*)sx;
      u16 e[8]; *(uint4*)e = xv;
      #pragma unroll
      for(int i = 0; i < 8; i++) As[ns + i][cl] = e[i];
    }
    {
      const int r = t >> 2, seg = (t & 3) * 16;
      const u16* sw = Wb + (size_t)(m0 + r) * 256 + kc + seg;
      uint2 w0 = *(const uint2*)sw;
      uint2 w1 = *(const uint2*)(sw + 4);
      uint2 w2 = *(const uint2*)(sw + 8);
      uint2 w3 = *(const uint2*)(sw + 12);
      *(uint2*)&Ws[r][seg]      = w0;
      *(uint2*)&Ws[r][seg + 4]  = w1;
      *(uint2*)&Ws[r][seg + 8]  = w2;
      *(uint2*)&Ws[r][seg + 12] = w3;
    }
    __syncthreads();
    #pragma unroll
    for(int ks = 0; ks < 2; ks++){
      const int kb = ks * 32 + fq * 8;
      bf16x8 a = ld_frag8(&As[w * 16 + fm][kb]);
      #pragma unroll
      for(int nt = 0; nt < 4; nt++){
        bf16x8 bb = ld_frag8(&Ws[nt * 16 + fm][kb]);
        acc[nt] = __builtin_amdgcn_mfma_f32_16x16x32_bf16(a, bb, acc[nt], 0, 0, 0);
      }
    }
    __syncthreads();
  }
  #pragma unroll
  for(int nt = 0; nt < 4; nt++){
    #pragma unroll
    for(int r = 0; r < 4; r++)
      Cs[nt * 16 + fm][w * 16 + fq * 4 + r] = acc[nt][r];
  }
  __syncthreads();
  {
    const int r = t >> 2, seg = (t & 3) * 16;
    uint4 o0, o1;
    u32 pk[8];
    #pragma unroll
    for(int i = 0; i < 8; i++)
      pk[i] = (u32)f2bf(Cs[r][seg + 2*i]) | ((u32)f2bf(Cs[r][seg + 2*i + 1]) << 16);
    o0.x = pk[0]; o0.y = pk[1]; o0.z = pk[2]; o0.w = pk[3];
    o1.x = pk[4]; o1.y = pk[5]; o1.z = pk[6]; o1.w = pk[7];
    u16* yp = Y + (size_t)(b * rows_per_b + m0 + r) * 4096 + n0 + seg;
    *(uint4*)yp = o0;
    *(uint4*)(yp + 8) = o1;
  }
}

// ---------------------------------------------------------------------------
// K2: xef[b,c,p] = sum_n xb[b,c,n] * EFf[n,p].  Block: 4 c x 64 p.
// ---------------------------------------------------------------------------
__global__ __launch_bounds__(256) void k_xef4(const u16* __restrict__ xb,
                                              const float* __restrict__ EFf,
                                              float* __restrict__ xef){
  const int t = threadIdx.x;
  const int ci = t >> 6, p = t & 63;
  const int c = blockIdx.x * 4 + ci, b = blockIdx.y;
  const u16* xr = xb + (size_t)(b * 256 + c) * 4096;
  float acc = 0.f;
  for(int n = 0; n < 4096; n++)
    acc += bf2f(xr[n]) * EFf[(size_t)n * 64 + p];
  xef[(size_t)(b * 256 + c) * 64 + p] = acc;
}

// ---------------------------------------------------------------------------
// K3: kvp[b, r, p] = sum_c W_sa[row_w(r), c] * xef[b, c, p]
// ---------------------------------------------------------------------------
__global__ __launch_bounds__(256) void k_kv4(const float* __restrict__ Wsaf,
                                             const float* __restrict__ xef,
                                             float* __restrict__ kvp){
  const int t = threadIdx.x;
  const int ri = t >> 6, p = t & 63;
  const int r = blockIdx.x * 4 + ri, b = blockIdx.y;
  const int row_w = (r < 256) ? (256 + r) : (512 + r);
  const float* wr = Wsaf + (size_t)row_w * 256;
  const float* xr = xef + (size_t)(b * 256) * 64 + p;
  float acc = 0.f;
  for(int c = 0; c < 256; c++)
    acc += wr[c] * xr[(size_t)c * 64];
  kvp[(size_t)(b * 512 + r) * 64 + p] = acc;
}

// ---------------------------------------------------------------------------
// K4: dst[b*256+r] = 1 / max(||row||_2, 1e-12), LDS tree reduction.
// ---------------------------------------------------------------------------
__global__ __launch_bounds__(256) void k_norm(const u16* __restrict__ src,
                                              float* __restrict__ dst,
                                              int stride_b, int row_off){
  __shared__ float red[256];
  const int r = blockIdx.x, b = blockIdx.y, t = threadIdx.x;
  const u16* row = src + (size_t)(b * stride_b + row_off + r) * 4096;
  float s = 0.f;
  #pragma unroll
  for(int i = 0; i < 16; i++){ float v = bf2f(row[t + 256 * i]); s += v * v; }
  red[t] = s;
  __syncthreads();
  for(int s2 = 128; s2 > 0; s2 >>= 1){
    if(t < s2) red[t] += red[t + s2];
    __syncthreads();
  }
  if(t == 0) dst[b * 256 + r] = 1.0f / fmaxf(sqrtf(red[0]), 1e-12f);
}

// ---------------------------------------------------------------------------
// K5: Gram partials over n-split s: Gp[s][b][h][j][e] = sum_n qc[j,n]*kc[e,n].
// ---------------------------------------------------------------------------
__global__ __launch_bounds__(256) void k_gram8(const u16* __restrict__ y_sc,
                                               float* __restrict__ Gp){
  const int t = threadIdx.x;
  const int s = blockIdx.x, h = blockIdx.y, b = blockIdx.z;
  const int j = t >> 3, e0 = (t & 7) * 4;
  const u16* qr = y_sc + (size_t)(b * 768 + h * 32 + j) * 4096;
  const u16* k0 = y_sc + (size_t)(b * 768 + 256 + h * 32 + e0) * 4096;
  float acc[4] = {};
  for(int n = s * 512; n < s * 512 + 512; n++){
    const float qv = bf2f(qr[n]);
    acc[0] += qv * bf2f(k0[n]);
    acc[1] += qv * bf2f(k0[n + 4096]);
    acc[2] += qv * bf2f(k0[n + 8192]);
    acc[3] += qv * bf2f(k0[n + 12288]);
  }
  float* dst = Gp + ((size_t)((s * 8 + b) * 8 + h) * 1024 + j * 32 + e0);
  #pragma unroll
  for(int i = 0; i < 4; i++) dst[i] = acc[i];
}

// ---------------------------------------------------------------------------
// K5b: attn[b][h][j][e] = softmax_e( (sum_s Gp) * invq[j] * invk[e] * temp[h] )
// ---------------------------------------------------------------------------
__global__ void k_softmax_ca(const float* __restrict__ Gp,
                             const float* __restrict__ invq,
                             const float* __restrict__ invk,
                             const float* __restrict__ temp,
                             float* __restrict__ attn){
  const int j = threadIdx.x, h = blockIdx.x, b = blockIdx.y;
  const float tm = temp[h];
  const float iq = invq[b * 256 + h * 32 + j];
  float v[32];
  float m = -1e30f;
  #pragma unroll
  for(int e = 0; e < 32; e++){
    float g = 0.f;
    #pragma unroll
    for(int s = 0; s < 8; s++)
      g += Gp[(size_t)s * 65536 + (size_t)(b * 8 + h) * 1024 + j * 32 + e];
    float val = g * iq * invk[b * 256 + h * 32 + e] * tm;
    v[e] = val; m = fmaxf(m, val);
  }
  float sum = 0.f;
  #pragma unroll
  for(int e = 0; e < 32; e++){ v[e] = __expf(v[e] - m); sum += v[e]; }
  const float inv = 1.0f / sum;
  #pragma unroll
  for(int e = 0; e < 32; e++) attn[(size_t)(b * 8 + h) * 1024 + j * 32 + e] = v[e] * inv;
}

// ---------------------------------------------------------------------------
// K6: spatial attention -> xsa[b][h][j][n] (bf16, natural layout).
// ---------------------------------------------------------------------------
__global__ __launch_bounds__(256) void k_sa8(const u16* __restrict__ q_sa,
                                             const float* __restrict__ kvp,
                                             const float* __restrict__ inv_sa,
                                             const float* __restrict__ temp2,
                                             u16* __restrict__ xsa){
  __shared__ float kp[2048];
  __shared__ float vp[2048];
  __shared__ float invl[32];
  const int t = threadIdx.x;
  const int ntile = blockIdx.x, h = blockIdx.y, b = blockIdx.z;
  {
    const float* ks = kvp + (size_t)(b * 512 + h * 32) * 64;        // k rows
    const float* vs = kvp + (size_t)(b * 512 + 256 + h * 32) * 64;  // v rows
    #pragma unroll
    for(int i = 0; i < 8; i++){
      kp[i * 256 + t] = ks[i * 256 + t];
      vp[i * 256 + t] = vs[i * 256 + t];
    }
    if(t < 32) invl[t] = inv_sa[b * 256 + h * 32 + t];
  }
  __syncthreads();
  const int n = ntile * 256 + t;
  float l[64];
  #pragma unroll
  for(int p = 0; p < 64; p++) l[p] = 0.f;
  for(int j = 0; j < 32; j++){
    const float qv = bf2f(q_sa[(size_t)(b * 256 + h * 32 + j) * 4096 + n]) * invl[j];
    const float4* k4 = (const float4*)&kp[j * 64];
    #pragma unroll
    for(int p4 = 0; p4 < 16; p4++){
      const float4 kv = k4[p4];
      l[p4*4+0] += qv*kv.x; l[p4*4+1] += qv*kv.y; l[p4*4+2] += qv*kv.z; l[p4*4+3] += qv*kv.w;
    }
  }
  const float tm = temp2[h];
  float m = -1e30f;
  #pragma unroll
  for(int p = 0; p < 64; p++){ l[p] *= tm; m = fmaxf(m, l[p]); }
  float sum = 0.f;
  #pragma unroll
  for(int p = 0; p < 64; p++){ l[p] = __expf(l[p] - m); sum += l[p]; }
  const float sinv = 1.0f / sum;
  for(int j = 0; j < 32; j++){
    const float4* v4 = (const float4*)&vp[j * 64];
    float s = 0.f;
    #pragma unroll
    for(int p4 = 0; p4 < 16; p4++){
      const float4 vv = v4[p4];
      s += l[p4*4+0]*vv.x + l[p4*4+1]*vv.y + l[p4*4+2]*vv.z + l[p4*4+3]*vv.w;
    }
    xsa[((size_t)(b * 8 + h) * 32 + j) * 4096 + n] = f2bf(s * sinv);
  }
}

// ---------------------------------------------------------------------------
// K7 (new): tiled out-writer. Block = (jg, h_c, b): 32 cc (one h_c) x 512 nn
// (j in [jg*4, jg*4+4)). All xsa/Vc data LDS-staged with coalesced reads;
// writes are lane-consecutive float2.
//   out[b, cc, nn] = sum_e attn[b,h_c,cc&31,e]*Vc[b,512+h_c*32+e,nn]
//                  + xsa[b, h, j, nh*256+cc],  nn = j*128+h*16+nh.
// Local nn_loc = nn - jg*512 = jj*128 + h*16 + nh;  hj := nn_loc>>4 = jj*8+h.
// ---------------------------------------------------------------------------
__global__ __launch_bounds__(256) void k_out2(const u16* __restrict__ y_sc,
                                              const float* __restrict__ attn,
                                              const u16* __restrict__ xsa,
                                              float* __restrict__ out){
  __shared__ u16 VcL[32][520];      // [e][nn_loc], pitch 520 (1040 B, 16B-divisible)
  __shared__ u16 xs[32][16][34];    // [hj][nh][cc_i], pitch 34
  __shared__ float arL[32][32];     // [j_c][e]
  const int t = threadIdx.x;
  const int jg = blockIdx.x, hc = blockIdx.y, b = blockIdx.z;
  const int nn0 = jg * 512;
  // stage attn (row-major copy)
  {
    const float* ap = attn + (size_t)(b * 8 + hc) * 1024;
    #pragma unroll
    for(int i = 0; i < 4; i++) ((float*)arL)[t + 256 * i] = ap[t + 256 * i];
  }
  // stage Vc: 32 rows x 512 u16, thread: e = t>>3, 64 u16 chunk
  {
    const int e = t >> 3, ch = (t & 7) * 64;
    const u16* src = y_sc + (size_t)(b * 768 + 512 + hc * 32 + e) * 4096 + nn0 + ch;
    #pragma unroll
    for(int i = 0; i < 8; i++)
      *(uint4*)&VcL[e][ch + i * 8] = *(const uint4*)(src + i * 8);
  }
  // stage xs: 512 segments of 32 u16; seg s: hj = s>>4 (jj = hj>>3, h = hj&7), nh = s&15
  #pragma unroll
  for(int rep = 0; rep < 2; rep++){
    const int s = rep * 256 + t;
    const int hj = s >> 4, nh = s & 15;
    const int h = hj & 7, jj = hj >> 3;
    const u16* src = xsa + ((size_t)(b * 8 + h) * 32 + jg * 4 + jj) * 4096 + nh * 256 + hc * 32;
    uint4 v0 = *(const uint4*)src;        // 16 u16
    uint4 v1 = *(const uint4*)(src + 8);
    u16* dst = &xs[hj][nh][0];
    u32* d32 = (u32*)dst;                 // base (hj*16+nh)*34 u16 -> 4B-aligned
    d32[0] = v0.x; d32[1] = v0.y; d32[2] = v0.z; d32[3] = v0.w;
    d32[4] = v1.x; d32[5] = v1.y; d32[6] = v1.z; d32[7] = v1.w;
    uint4 v2 = *(const uint4*)(src + 16);
    uint4 v3 = *(const uint4*)(src + 24);
    d32[8]  = v2.x; d32[9]  = v2.y; d32[10] = v2.z; d32[11] = v2.w;
    d32[12] = v3.x; d32[13] = v3.y; d32[14] = v3.z; d32[15] = v3.w;
  }
  __syncthreads();
  // compute: thread t owns cols nn_loc = 2t, 2t+1 for every row (cc)
  const int nl0 = 2 * t, nl1 = 2 * t + 1;
  const int hj0 = nl0 >> 4, nh0 = nl0 & 15;   // nl1: same hj, nh0+1
  for(int row = 0; row < 32; row++){
    float acc0 = 0.f, acc1 = 0.f;
    #pragma unroll
    for(int e = 0; e < 32; e++){
      const float a = arL[row][e];                       // wave-uniform broadcast
      const u32 v = *(const u32*)&VcL[e][nl0];           // lane-consecutive u32
      acc0 += a * bf2f((u16)(v & 0xFFFF));
      acc1 += a * bf2f((u16)(v >> 16));
    }
    const float sa0 = bf2f(xs[hj0][nh0][row]);
    const float sa1 = bf2f(xs[hj0][nh0 + 1][row]);
    float2 o; o.x = acc0 + sa0; o.y = acc1 + sa1;
    *(float2*)&out[(size_t)(b * 256 + hc * 32 + row) * 4096 + nn0 + nl0] = o;
  }
}

// ---------------------------------------------------------------------------
// Workspace layout (bytes), total ~91.0 MB (unchanged).
// ---------------------------------------------------------------------------
#define OFF_XB    ((size_t)0)           // u16 [8][256][4096] 16,777,216 (reused as xsa)
#define OFF_QSA   ((size_t)16777216)    // u16 [8][256][4096] 16,777,216
#define OFF_YSC   ((size_t)33554432)    // u16 [8][768][4096] 50,331,648
#define OFF_WSAF  ((size_t)83886080)    // f32 [1024][256]     1,048,576
#define OFF_WBSA  ((size_t)84934656)    // u16 [1024][256]       524,288
#define OFF_WBSC  ((size_t)85458944)    // u16 [1024][256]       524,288
#define OFF_EFF   ((size_t)85983232)    // f32 [4096][64]      1,048,576
#define OFF_XEF   ((size_t)87031808)    // f32 [8][256][64]      524,288
#define OFF_KVP   ((size_t)87556096)    // f32 [8][512][64]    1,048,576
#define OFF_ISA   ((size_t)88604672)    // f32 [8][256]            8,192
#define OFF_IQC   ((size_t)88612864)
#define OFF_IKC   ((size_t)88621056)
#define OFF_GP    ((size_t)88629248)    // f32 [8][8][8][32][32] 2,097,152
#define OFF_ATT   ((size_t)90726400)    // f32 [8][8][32][32]    262,144
#define OFF_TF    ((size_t)90988544)    // f32 [16]
#define OFF_FLAG  ((size_t)90988608)    // u32

extern "C" void kernel_launch(void* const* d_in, const int* in_sizes, int n_in,
                              void* d_out, int out_size, void* d_ws, size_t ws_size,
                              hipStream_t stream){
  (void)in_sizes; (void)n_in; (void)out_size; (void)ws_size;
  char* ws = (char*)d_ws;
  u16*   xb    = (u16*)  (ws + OFF_XB);
  u16*   xsa   = (u16*)  (ws + OFF_XB);    // overlay: xb dead after gemms/xef4
  u16*   q_sa  = (u16*)  (ws + OFF_QSA);
  u16*   y_sc  = (u16*)  (ws + OFF_YSC);
  float* Wsaf  = (float*)(ws + OFF_WSAF);
  u16*   WbSA  = (u16*)  (ws + OFF_WBSA);
  u16*   WbSC  = (u16*)  (ws + OFF_WBSC);
  float* EFf   = (float*)(ws + OFF_EFF);
  float* xef   = (float*)(ws + OFF_XEF);
  float* kvp   = (float*)(ws + OFF_KVP);
  float* invsa = (float*)(ws + OFF_ISA);
  float* invqc = (float*)(ws + OFF_IQC);
  float* invkc = (float*)(ws + OFF_IKC);
  float* Gp    = (float*)(ws + OFF_GP);
  float* attn  = (float*)(ws + OFF_ATT);
  float* tf    = (float*)(ws + OFF_TF);
  u32*   flag  = (u32*)  (ws + OFF_FLAG);
  float* out = (float*)d_out;

  // dtype detect + canonicalize
  k_detect<<<1, 256, 0, stream>>>((const u16*)d_in[0], flag);
  k_conv_bf  <<<4096, 256, 0, stream>>>(d_in[0], xb, 8388608, flag);          // x -> bf16
  k_conv_both<<<256,  256, 0, stream>>>(d_in[1], Wsaf, WbSA, 262144, flag);   // W_sa -> f32+bf16
  k_conv_f32 <<<256,  256, 0, stream>>>(d_in[2], EFf, 262144, flag);          // EF -> f32
  k_conv_bf  <<<128,  256, 0, stream>>>(d_in[4], WbSC, 262144, flag);         // W_sc -> bf16
  k_conv_f32 <<<1,    256, 0, stream>>>(d_in[3], tf,      8, flag);           // temp2_sa
  k_conv_f32 <<<1,    256, 0, stream>>>(d_in[5], tf + 8,  8, flag);           // temp_sc

  // QKV GEMMs (MFMA)
  k_gemm_mfma<<<dim3(64, 4, 8),  256, 0, stream>>>(WbSA, xb, q_sa, 256);
  k_gemm_mfma<<<dim3(64, 12, 8), 256, 0, stream>>>(WbSC, xb, y_sc, 768);
  // Linformer projection via associativity
  k_xef4<<<dim3(64, 8),  256, 0, stream>>>(xb, EFf, xef);
  k_kv4 <<<dim3(128, 8), 256, 0, stream>>>(Wsaf, xef, kvp);
  // L2 norms (reciprocals)
  k_norm<<<dim3(256, 8), 256, 0, stream>>>(q_sa, invsa, 256, 0);
  k_norm<<<dim3(256, 8), 256, 0, stream>>>(y_sc, invqc, 768, 0);
  k_norm<<<dim3(256, 8), 256, 0, stream>>>(y_sc, invkc, 768, 256);
  // Channel attention matrix
  k_gram8<<<dim3(8, 8, 8), 256, 0, stream>>>(y_sc, Gp);
  k_softmax_ca<<<dim3(8, 8), 32, 0, stream>>>(Gp, invqc, invkc, tf + 8, attn);
  // Spatial attention -> xsa, then tiled scramble-gather -> fp32 out
  k_sa8<<<dim3(16, 8, 8), 256, 0, stream>>>(q_sa, kvp, invsa, tf, xsa);
  k_out2<<<dim3(8, 8, 8), 256, 0, stream>>>(y_sc, attn, xsa, out);
}

// Round 10
// 437.188 us; speedup vs baseline: 1.9669x; 1.2534x over previous
//
#include <hip/hip_runtime.h>

typedef unsigned short u16;
typedef unsigned int   u32;

typedef __attribute__((ext_vector_type(4))) short short4v;
typedef __attribute__((ext_vector_type(8))) short bf16x8;  // 8 bf16 (4 VGPRs)
typedef __attribute__((ext_vector_type(4))) float f32x4;

// Problem: B=8, C=256, N=4096, heads=8, d=32, P=64. Inputs fp32 (auto-detect),
// output FP32. r8: MFMA GEMMs. r9: tiled k_out2. r10: split-K LDS-tiled xef.

__device__ __forceinline__ float bf2f(u16 u){
  union { u32 i; float f; } v; v.i = ((u32)u) << 16; return v.f;
}
__device__ __forceinline__ u16 f2bf(float f){
  u32 u = __float_as_uint(f);
  u32 r = u + 0x7FFFu + ((u >> 16) & 1u);   // RNE
  return (u16)(r >> 16);
}

// ---------------------------------------------------------------------------
// K0a: dtype detector on x. flag=1 => fp32 input.
// ---------------------------------------------------------------------------
__global__ void k_detect(const u16* __restrict__ x, u32* __restrict__ flag){
  __shared__ int cnt[256];
  const int t = threadIdx.x;
  int c = 0;
  #pragma unroll
  for(int i = 0; i < 4; i++){
    u16 v = x[t * 4 + i];
    int e = (v >> 7) & 0xFF;
    if(e >= 112 && e <= 134) c++;
  }
  cnt[t] = c;
  __syncthreads();
  for(int s = 128; s > 0; s >>= 1){
    if(t < s) cnt[t] += cnt[t + s];
    __syncthreads();
  }
  if(t == 0) *flag = (cnt[0] < 800) ? 1u : 0u;
}

// ---------------------------------------------------------------------------
// K0b: canonicalize to bf16 (8 elems/thread).
// ---------------------------------------------------------------------------
__global__ __launch_bounds__(256) void k_conv_bf(const void* __restrict__ src,
                                                 u16* __restrict__ dst, int n,
                                                 const u32* __restrict__ flag){
  const int i0 = (blockIdx.x * 256 + threadIdx.x) * 8;
  if(i0 >= n) return;
  const bool isf32 = (*flag != 0);
  if(isf32){
    const float4 a = *(const float4*)((const float*)src + i0);
    const float4 b = *(const float4*)((const float*)src + i0 + 4);
    uint4 o;
    o.x = (u32)f2bf(a.x) | ((u32)f2bf(a.y) << 16);
    o.y = (u32)f2bf(a.z) | ((u32)f2bf(a.w) << 16);
    o.z = (u32)f2bf(b.x) | ((u32)f2bf(b.y) << 16);
    o.w = (u32)f2bf(b.z) | ((u32)f2bf(b.w) << 16);
    *(uint4*)(dst + i0) = o;
  } else {
    *(uint4*)(dst + i0) = *(const uint4*)((const u16*)src + i0);
  }
}

// ---------------------------------------------------------------------------
// K0c: canonicalize to fp32 (4 elems/thread).
// ---------------------------------------------------------------------------
__global__ __launch_bounds__(256) void k_conv_f32(const void* __restrict__ src,
                                                  float* __restrict__ dst, int n,
                                                  const u32* __restrict__ flag){
  const int i0 = (blockIdx.x * 256 + threadIdx.x) * 4;
  if(i0 >= n) return;
  const bool isf32 = (*flag != 0);
  if(isf32){
    *(float4*)(dst + i0) = *(const float4*)((const float*)src + i0);
  } else {
    const uint2 a = *(const uint2*)((const u16*)src + i0);
    float4 o;
    o.x = bf2f((u16)(a.x & 0xFFFF)); o.y = bf2f((u16)(a.x >> 16));
    o.z = bf2f((u16)(a.y & 0xFFFF)); o.w = bf2f((u16)(a.y >> 16));
    *(float4*)(dst + i0) = o;
  }
}

// ---------------------------------------------------------------------------
// K0d: canonicalize to BOTH fp32 and bf16 (4 elems/thread) — for W_sa.
// ---------------------------------------------------------------------------
__global__ __launch_bounds__(256) void k_conv_both(const void* __restrict__ src,
                                                   float* __restrict__ dstf,
                                                   u16* __restrict__ dstb, int n,
                                                   const u32* __restrict__ flag){
  const int i0 = (blockIdx.x * 256 + threadIdx.x) * 4;
  if(i0 >= n) return;
  const bool isf32 = (*flag != 0);
  float4 o;
  if(isf32){
    o = *(const float4*)((const float*)src + i0);
  } else {
    const uint2 a = *(const uint2*)((const u16*)src + i0);
    o.x = bf2f((u16)(a.x & 0xFFFF)); o.y = bf2f((u16)(a.x >> 16));
    o.z = bf2f((u16)(a.y & 0xFFFF)); o.w = bf2f((u16)(a.y >> 16));
  }
  *(float4*)(dstf + i0) = o;
  uint2 pk;
  pk.x = (u32)f2bf(o.x) | ((u32)f2bf(o.y) << 16);
  pk.y = (u32)f2bf(o.z) | ((u32)f2bf(o.w) << 16);
  *(uint2*)(dstb + i0) = pk;
}

// ---------------------------------------------------------------------------
// K1: MFMA GEMM (unchanged from r8).
// ---------------------------------------------------------------------------
__device__ __forceinline__ bf16x8 ld_frag8(const u16* p){
  short4v lo = *(const short4v*)p;
  short4v hi = *(const short4v*)(p + 4);
  bf16x8 r;
  r[0]=lo[0]; r[1]=lo[1]; r[2]=lo[2]; r[3]=lo[3];
  r[4]=hi[0]; r[5]=hi[1]; r[6]=hi[2]; r[7]=hi[3];
  return r;
}

__global__ __launch_bounds__(256) void k_gemm_mfma(const u16* __restrict__ Wb,
                                                   const u16* __restrict__ xb,
                                                   u16* __restrict__ Y,
                                                   int rows_per_b){
  __shared__ u16 As[64][68];
  __shared__ u16 Ws[64][68];
  __shared__ float Cs[64][69];
  const int t = threadIdx.x;
  const int n0 = blockIdx.x * 64, m0 = blockIdx.y * 64, b = blockIdx.z;
  const int lane = t & 63, w = t >> 6;
  const int fm = lane & 15, fq = lane >> 4;
  f32x4 acc[4] = {};
  for(int kc = 0; kc < 256; kc += 64){
    #pragma unroll
    for(int half = 0; half < 2; half++){
      const int cl = half * 32 + (t >> 3);
      const int ns = (t & 7) * 8;
      const u16* sx = xb + (size_t)(b * 256 + kc + cl) * 4096 + n0 + ns;
      uint4 xv = *(const uint4*)sx;
      u16 e[8]; *(uint4*)e = xv;
      #pragma unroll
      for(int i = 0; i < 8; i++) As[ns + i][cl] = e[i];
    }
    {
      const int r = t >> 2, seg = (t & 3) * 16;
      const u16* sw = Wb + (size_t)(m0 + r) * 256 + kc + seg;
      uint2 w0 = *(const uint2*)sw;
      uint2 w1 = *(const uint2*)(sw + 4);
      uint2 w2 = *(const uint2*)(sw + 8);
      uint2 w3 = *(const uint2*)(sw + 12);
      *(uint2*)&Ws[r][seg]      = w0;
      *(uint2*)&Ws[r][seg + 4]  = w1;
      *(uint2*)&Ws[r][seg + 8]  = w2;
      *(uint2*)&Ws[r][seg + 12] = w3;
    }
    __syncthreads();
    #pragma unroll
    for(int ks = 0; ks < 2; ks++){
      const int kb = ks * 32 + fq * 8;
      bf16x8 a = ld_frag8(&As[w * 16 + fm][kb]);
      #pragma unroll
      for(int nt = 0; nt < 4; nt++){
        bf16x8 bb = ld_frag8(&Ws[nt * 16 + fm][kb]);
        acc[nt] = __builtin_amdgcn_mfma_f32_16x16x32_bf16(a, bb, acc[nt], 0, 0, 0);
      }
    }
    __syncthreads();
  }
  #pragma unroll
  for(int nt = 0; nt < 4; nt++){
    #pragma unroll
    for(int r = 0; r < 4; r++)
      Cs[nt * 16 + fm][w * 16 + fq * 4 + r] = acc[nt][r];
  }
  __syncthreads();
  {
    const int r = t >> 2, seg = (t & 3) * 16;
    uint4 o0, o1;
    u32 pk[8];
    #pragma unroll
    for(int i = 0; i < 8; i++)
      pk[i] = (u32)f2bf(Cs[r][seg + 2*i]) | ((u32)f2bf(Cs[r][seg + 2*i + 1]) << 16);
    o0.x = pk[0]; o0.y = pk[1]; o0.z = pk[2]; o0.w = pk[3];
    o1.x = pk[4]; o1.y = pk[5]; o1.z = pk[6]; o1.w = pk[7];
    u16* yp = Y + (size_t)(b * rows_per_b + m0 + r) * 4096 + n0 + seg;
    *(uint4*)yp = o0;
    *(uint4*)(yp + 8) = o1;
  }
}

// ---------------------------------------------------------------------------
// K2 (new): split-K LDS-tiled xef partials.
// xefp[s][b][c][p] = sum_{n in split s (512)} xb[b,c,n] * EFf[n,p]
// Block = 32 c x 64 p; LDS-staged x (32x64 bf16->f32) and EF (64x64 f32).
// grid (8 ctile, 8 split, 8 b) = 512 blocks.
// ---------------------------------------------------------------------------
__global__ __launch_bounds__(256) void k_xef8(const u16* __restrict__ xb,
                                              const float* __restrict__ EFf,
                                              float* __restrict__ xefp){
  __shared__ float At[32][68];  // [c][k]
  __shared__ float Bt[64][72];  // [k][p]
  const int t = threadIdx.x;
  const int c0 = blockIdx.x * 32, s = blockIdx.y, b = blockIdx.z;
  const int cc = t >> 3, p0 = (t & 7) * 8;
  float acc[8] = {};
  for(int n0 = s * 512; n0 < s * 512 + 512; n0 += 64){
    {
      const int r = t >> 3, k0 = (t & 7) * 8;
      const u16* sx = xb + (size_t)(b * 256 + c0 + r) * 4096 + n0 + k0;
      uint4 xv = *(const uint4*)sx;
      u16 e[8]; *(uint4*)e = xv;
      #pragma unroll
      for(int i = 0; i < 8; i++) At[r][k0 + i] = bf2f(e[i]);
      const int rk = t >> 2, pp = (t & 3) * 16;
      const float* se = EFf + (size_t)(n0 + rk) * 64 + pp;
      #pragma unroll
      for(int i = 0; i < 4; i++)
        *(float4*)&Bt[rk][pp + i * 4] = *(const float4*)(se + i * 4);
    }
    __syncthreads();
    #pragma unroll 8
    for(int kk = 0; kk < 64; kk++){
      const float a = At[cc][kk];
      const float4 b0 = *(const float4*)&Bt[kk][p0];
      const float4 b1 = *(const float4*)&Bt[kk][p0 + 4];
      acc[0] += a*b0.x; acc[1] += a*b0.y; acc[2] += a*b0.z; acc[3] += a*b0.w;
      acc[4] += a*b1.x; acc[5] += a*b1.y; acc[6] += a*b1.z; acc[7] += a*b1.w;
    }
    __syncthreads();
  }
  float* dst = xefp + ((size_t)s * 131072 + (size_t)(b * 256 + c0 + cc) * 64 + p0);
  #pragma unroll
  for(int i = 0; i < 8; i++) dst[i] = acc[i];
}

// ---------------------------------------------------------------------------
// K2b: reduce partials: xef[i] = sum_s xefp[s][i], i over [0, 131072), float4.
// ---------------------------------------------------------------------------
__global__ __launch_bounds__(256) void k_xred(const float* __restrict__ xefp,
                                              float* __restrict__ xef){
  const int i0 = (blockIdx.x * 256 + threadIdx.x) * 4;
  float4 a = *(const float4*)(xefp + i0);
  #pragma unroll
  for(int s = 1; s < 8; s++){
    const float4 v = *(const float4*)(xefp + (size_t)s * 131072 + i0);
    a.x += v.x; a.y += v.y; a.z += v.z; a.w += v.w;
  }
  *(float4*)(xef + i0) = a;
}

// ---------------------------------------------------------------------------
// K3: kvp[b, r, p] = sum_c W_sa[row_w(r), c] * xef[b, c, p]
// ---------------------------------------------------------------------------
__global__ __launch_bounds__(256) void k_kv4(const float* __restrict__ Wsaf,
                                             const float* __restrict__ xef,
                                             float* __restrict__ kvp){
  const int t = threadIdx.x;
  const int ri = t >> 6, p = t & 63;
  const int r = blockIdx.x * 4 + ri, b = blockIdx.y;
  const int row_w = (r < 256) ? (256 + r) : (512 + r);
  const float* wr = Wsaf + (size_t)row_w * 256;
  const float* xr = xef + (size_t)(b * 256) * 64 + p;
  float acc = 0.f;
  for(int c = 0; c < 256; c++)
    acc += wr[c] * xr[(size_t)c * 64];
  kvp[(size_t)(b * 512 + r) * 64 + p] = acc;
}

// ---------------------------------------------------------------------------
// K4: dst[b*256+r] = 1 / max(||row||_2, 1e-12), LDS tree reduction.
// ---------------------------------------------------------------------------
__global__ __launch_bounds__(256) void k_norm(const u16* __restrict__ src,
                                              float* __restrict__ dst,
                                              int stride_b, int row_off){
  __shared__ float red[256];
  const int r = blockIdx.x, b = blockIdx.y, t = threadIdx.x;
  const u16* row = src + (size_t)(b * stride_b + row_off + r) * 4096;
  float s = 0.f;
  #pragma unroll
  for(int i = 0; i < 16; i++){ float v = bf2f(row[t + 256 * i]); s += v * v; }
  red[t] = s;
  __syncthreads();
  for(int s2 = 128; s2 > 0; s2 >>= 1){
    if(t < s2) red[t] += red[t + s2];
    __syncthreads();
  }
  if(t == 0) dst[b * 256 + r] = 1.0f / fmaxf(sqrtf(red[0]), 1e-12f);
}

// ---------------------------------------------------------------------------
// K5: Gram partials over n-split s: Gp[s][b][h][j][e] = sum_n qc[j,n]*kc[e,n].
// ---------------------------------------------------------------------------
__global__ __launch_bounds__(256) void k_gram8(const u16* __restrict__ y_sc,
                                               float* __restrict__ Gp){
  const int t = threadIdx.x;
  const int s = blockIdx.x, h = blockIdx.y, b = blockIdx.z;
  const int j = t >> 3, e0 = (t & 7) * 4;
  const u16* qr = y_sc + (size_t)(b * 768 + h * 32 + j) * 4096;
  const u16* k0 = y_sc + (size_t)(b * 768 + 256 + h * 32 + e0) * 4096;
  float acc[4] = {};
  for(int n = s * 512; n < s * 512 + 512; n++){
    const float qv = bf2f(qr[n]);
    acc[0] += qv * bf2f(k0[n]);
    acc[1] += qv * bf2f(k0[n + 4096]);
    acc[2] += qv * bf2f(k0[n + 8192]);
    acc[3] += qv * bf2f(k0[n + 12288]);
  }
  float* dst = Gp + ((size_t)((s * 8 + b) * 8 + h) * 1024 + j * 32 + e0);
  #pragma unroll
  for(int i = 0; i < 4; i++) dst[i] = acc[i];
}

// ---------------------------------------------------------------------------
// K5b: attn[b][h][j][e] = softmax_e( (sum_s Gp) * invq[j] * invk[e] * temp[h] )
// ---------------------------------------------------------------------------
__global__ void k_softmax_ca(const float* __restrict__ Gp,
                             const float* __restrict__ invq,
                             const float* __restrict__ invk,
                             const float* __restrict__ temp,
                             float* __restrict__ attn){
  const int j = threadIdx.x, h = blockIdx.x, b = blockIdx.y;
  const float tm = temp[h];
  const float iq = invq[b * 256 + h * 32 + j];
  float v[32];
  float m = -1e30f;
  #pragma unroll
  for(int e = 0; e < 32; e++){
    float g = 0.f;
    #pragma unroll
    for(int s = 0; s < 8; s++)
      g += Gp[(size_t)s * 65536 + (size_t)(b * 8 + h) * 1024 + j * 32 + e];
    float val = g * iq * invk[b * 256 + h * 32 + e] * tm;
    v[e] = val; m = fmaxf(m, val);
  }
  float sum = 0.f;
  #pragma unroll
  for(int e = 0; e < 32; e++){ v[e] = __expf(v[e] - m); sum += v[e]; }
  const float inv = 1.0f / sum;
  #pragma unroll
  for(int e = 0; e < 32; e++) attn[(size_t)(b * 8 + h) * 1024 + j * 32 + e] = v[e] * inv;
}

// ---------------------------------------------------------------------------
// K6: spatial attention -> xsa[b][h][j][n] (bf16, natural layout).
// ---------------------------------------------------------------------------
__global__ __launch_bounds__(256) void k_sa8(const u16* __restrict__ q_sa,
                                             const float* __restrict__ kvp,
                                             const float* __restrict__ inv_sa,
                                             const float* __restrict__ temp2,
                                             u16* __restrict__ xsa){
  __shared__ float kp[2048];
  __shared__ float vp[2048];
  __shared__ float invl[32];
  const int t = threadIdx.x;
  const int ntile = blockIdx.x, h = blockIdx.y, b = blockIdx.z;
  {
    const float* ks = kvp + (size_t)(b * 512 + h * 32) * 64;
    const float* vs = kvp + (size_t)(b * 512 + 256 + h * 32) * 64;
    #pragma unroll
    for(int i = 0; i < 8; i++){
      kp[i * 256 + t] = ks[i * 256 + t];
      vp[i * 256 + t] = vs[i * 256 + t];
    }
    if(t < 32) invl[t] = inv_sa[b * 256 + h * 32 + t];
  }
  __syncthreads();
  const int n = ntile * 256 + t;
  float l[64];
  #pragma unroll
  for(int p = 0; p < 64; p++) l[p] = 0.f;
  for(int j = 0; j < 32; j++){
    const float qv = bf2f(q_sa[(size_t)(b * 256 + h * 32 + j) * 4096 + n]) * invl[j];
    const float4* k4 = (const float4*)&kp[j * 64];
    #pragma unroll
    for(int p4 = 0; p4 < 16; p4++){
      const float4 kv = k4[p4];
      l[p4*4+0] += qv*kv.x; l[p4*4+1] += qv*kv.y; l[p4*4+2] += qv*kv.z; l[p4*4+3] += qv*kv.w;
    }
  }
  const float tm = temp2[h];
  float m = -1e30f;
  #pragma unroll
  for(int p = 0; p < 64; p++){ l[p] *= tm; m = fmaxf(m, l[p]); }
  float sum = 0.f;
  #pragma unroll
  for(int p = 0; p < 64; p++){ l[p] = __expf(l[p] - m); sum += l[p]; }
  const float sinv = 1.0f / sum;
  for(int j = 0; j < 32; j++){
    const float4* v4 = (const float4*)&vp[j * 64];
    float s = 0.f;
    #pragma unroll
    for(int p4 = 0; p4 < 16; p4++){
      const float4 vv = v4[p4];
      s += l[p4*4+0]*vv.x + l[p4*4+1]*vv.y + l[p4*4+2]*vv.z + l[p4*4+3]*vv.w;
    }
    xsa[((size_t)(b * 8 + h) * 32 + j) * 4096 + n] = f2bf(s * sinv);
  }
}

// ---------------------------------------------------------------------------
// K7: tiled out-writer (unchanged from r9).
// ---------------------------------------------------------------------------
__global__ __launch_bounds__(256) void k_out2(const u16* __restrict__ y_sc,
                                              const float* __restrict__ attn,
                                              const u16* __restrict__ xsa,
                                              float* __restrict__ out){
  __shared__ u16 VcL[32][520];
  __shared__ u16 xs[32][16][34];
  __shared__ float arL[32][32];
  const int t = threadIdx.x;
  const int jg = blockIdx.x, hc = blockIdx.y, b = blockIdx.z;
  const int nn0 = jg * 512;
  {
    const float* ap = attn + (size_t)(b * 8 + hc) * 1024;
    #pragma unroll
    for(int i = 0; i < 4; i++) ((float*)arL)[t + 256 * i] = ap[t + 256 * i];
  }
  {
    const int e = t >> 3, ch = (t & 7) * 64;
    const u16* src = y_sc + (size_t)(b * 768 + 512 + hc * 32 + e) * 4096 + nn0 + ch;
    #pragma unroll
    for(int i = 0; i < 8; i++)
      *(uint4*)&VcL[e][ch + i * 8] = *(const uint4*)(src + i * 8);
  }
  #pragma unroll
  for(int rep = 0; rep < 2; rep++){
    const int s = rep * 256 + t;
    const int hj = s >> 4, nh = s & 15;
    const int h = hj & 7, jj = hj >> 3;
    const u16* src = xsa + ((size_t)(b * 8 + h) * 32 + jg * 4 + jj) * 4096 + nh * 256 + hc * 32;
    uint4 v0 = *(const uint4*)src;
    uint4 v1 = *(const uint4*)(src + 8);
    u16* dst = &xs[hj][nh][0];
    u32* d32 = (u32*)dst;
    d32[0] = v0.x; d32[1] = v0.y; d32[2] = v0.z; d32[3] = v0.w;
    d32[4] = v1.x; d32[5] = v1.y; d32[6] = v1.z; d32[7] = v1.w;
    uint4 v2 = *(const uint4*)(src + 16);
    uint4 v3 = *(const uint4*)(src + 24);
    d32[8]  = v2.x; d32[9]  = v2.y; d32[10] = v2.z; d32[11] = v2.w;
    d32[12] = v3.x; d32[13] = v3.y; d32[14] = v3.z; d32[15] = v3.w;
  }
  __syncthreads();
  const int nl0 = 2 * t;
  const int hj0 = nl0 >> 4, nh0 = nl0 & 15;
  for(int row = 0; row < 32; row++){
    float acc0 = 0.f, acc1 = 0.f;
    #pragma unroll
    for(int e = 0; e < 32; e++){
      const float a = arL[row][e];
      const u32 v = *(const u32*)&VcL[e][nl0];
      acc0 += a * bf2f((u16)(v & 0xFFFF));
      acc1 += a * bf2f((u16)(v >> 16));
    }
    const float sa0 = bf2f(xs[hj0][nh0][row]);
    const float sa1 = bf2f(xs[hj0][nh0 + 1][row]);
    float2 o; o.x = acc0 + sa0; o.y = acc1 + sa1;
    *(float2*)&out[(size_t)(b * 256 + hc * 32 + row) * 4096 + nn0 + nl0] = o;
  }
}

// ---------------------------------------------------------------------------
// Workspace layout (bytes), total ~95.2 MB.
// ---------------------------------------------------------------------------
#define OFF_XB    ((size_t)0)           // u16 [8][256][4096] 16,777,216 (reused as xsa)
#define OFF_QSA   ((size_t)16777216)    // u16 [8][256][4096] 16,777,216
#define OFF_YSC   ((size_t)33554432)    // u16 [8][768][4096] 50,331,648
#define OFF_WSAF  ((size_t)83886080)    // f32 [1024][256]     1,048,576
#define OFF_WBSA  ((size_t)84934656)    // u16 [1024][256]       524,288
#define OFF_WBSC  ((size_t)85458944)    // u16 [1024][256]       524,288
#define OFF_EFF   ((size_t)85983232)    // f32 [4096][64]      1,048,576
#define OFF_XEF   ((size_t)87031808)    // f32 [8][256][64]      524,288
#define OFF_KVP   ((size_t)87556096)    // f32 [8][512][64]    1,048,576
#define OFF_ISA   ((size_t)88604672)    // f32 [8][256]            8,192
#define OFF_IQC   ((size_t)88612864)
#define OFF_IKC   ((size_t)88621056)
#define OFF_GP    ((size_t)88629248)    // f32 [8][8][8][32][32] 2,097,152
#define OFF_ATT   ((size_t)90726400)    // f32 [8][8][32][32]    262,144
#define OFF_TF    ((size_t)90988544)    // f32 [16]
#define OFF_FLAG  ((size_t)90988608)    // u32
#define OFF_XEFP  ((size_t)90992640)    // f32 [8][8][256][64] 4,194,304

extern "C" void kernel_launch(void* const* d_in, const int* in_sizes, int n_in,
                              void* d_out, int out_size, void* d_ws, size_t ws_size,
                              hipStream_t stream){
  (void)in_sizes; (void)n_in; (void)out_size; (void)ws_size;
  char* ws = (char*)d_ws;
  u16*   xb    = (u16*)  (ws + OFF_XB);
  u16*   xsa   = (u16*)  (ws + OFF_XB);    // overlay: xb dead after gemms/xef8
  u16*   q_sa  = (u16*)  (ws + OFF_QSA);
  u16*   y_sc  = (u16*)  (ws + OFF_YSC);
  float* Wsaf  = (float*)(ws + OFF_WSAF);
  u16*   WbSA  = (u16*)  (ws + OFF_WBSA);
  u16*   WbSC  = (u16*)  (ws + OFF_WBSC);
  float* EFf   = (float*)(ws + OFF_EFF);
  float* xef   = (float*)(ws + OFF_XEF);
  float* kvp   = (float*)(ws + OFF_KVP);
  float* invsa = (float*)(ws + OFF_ISA);
  float* invqc = (float*)(ws + OFF_IQC);
  float* invkc = (float*)(ws + OFF_IKC);
  float* Gp    = (float*)(ws + OFF_GP);
  float* attn  = (float*)(ws + OFF_ATT);
  float* tf    = (float*)(ws + OFF_TF);
  u32*   flag  = (u32*)  (ws + OFF_FLAG);
  float* xefp  = (float*)(ws + OFF_XEFP);
  float* out = (float*)d_out;

  // dtype detect + canonicalize
  k_detect<<<1, 256, 0, stream>>>((const u16*)d_in[0], flag);
  k_conv_bf  <<<4096, 256, 0, stream>>>(d_in[0], xb, 8388608, flag);          // x -> bf16
  k_conv_both<<<256,  256, 0, stream>>>(d_in[1], Wsaf, WbSA, 262144, flag);   // W_sa -> f32+bf16
  k_conv_f32 <<<256,  256, 0, stream>>>(d_in[2], EFf, 262144, flag);          // EF -> f32
  k_conv_bf  <<<128,  256, 0, stream>>>(d_in[4], WbSC, 262144, flag);         // W_sc -> bf16
  k_conv_f32 <<<1,    256, 0, stream>>>(d_in[3], tf,      8, flag);           // temp2_sa
  k_conv_f32 <<<1,    256, 0, stream>>>(d_in[5], tf + 8,  8, flag);           // temp_sc

  // QKV GEMMs (MFMA)
  k_gemm_mfma<<<dim3(64, 4, 8),  256, 0, stream>>>(WbSA, xb, q_sa, 256);
  k_gemm_mfma<<<dim3(64, 12, 8), 256, 0, stream>>>(WbSC, xb, y_sc, 768);
  // Linformer projection: split-K xef partials + reduce, then kvp
  k_xef8<<<dim3(8, 8, 8), 256, 0, stream>>>(xb, EFf, xefp);
  k_xred<<<128, 256, 0, stream>>>(xefp, xef);
  k_kv4 <<<dim3(128, 8), 256, 0, stream>>>(Wsaf, xef, kvp);
  // L2 norms (reciprocals)
  k_norm<<<dim3(256, 8), 256, 0, stream>>>(q_sa, invsa, 256, 0);
  k_norm<<<dim3(256, 8), 256, 0, stream>>>(y_sc, invqc, 768, 0);
  k_norm<<<dim3(256, 8), 256, 0, stream>>>(y_sc, invkc, 768, 256);
  // Channel attention matrix
  k_gram8<<<dim3(8, 8, 8), 256, 0, stream>>>(y_sc, Gp);
  k_softmax_ca<<<dim3(8, 8), 32, 0, stream>>>(Gp, invqc, invkc, tf + 8, attn);
  // Spatial attention -> xsa, then tiled scramble-gather -> fp32 out
  k_sa8<<<dim3(16, 8, 8), 256, 0, stream>>>(q_sa, kvp, invsa, tf, xsa);
  k_out2<<<dim3(8, 8, 8), 256, 0, stream>>>(y_sc, attn, xsa, out);
}

// Round 11
// 327.357 us; speedup vs baseline: 2.6268x; 1.3355x over previous
//
#include <hip/hip_runtime.h>

typedef unsigned short u16;
typedef unsigned int   u32;

typedef __attribute__((ext_vector_type(4))) short short4v;
typedef __attribute__((ext_vector_type(8))) short bf16x8;  // 8 bf16 (4 VGPRs)
typedef __attribute__((ext_vector_type(4))) float f32x4;

// Problem: B=8, C=256, N=4096, heads=8, d=32, P=64. Inputs fp32 (auto-detect),
// output FP32. r8: MFMA GEMMs. r9: tiled k_out2. r10: split-K xef. r11: MFMA gram.

__device__ __forceinline__ float bf2f(u16 u){
  union { u32 i; float f; } v; v.i = ((u32)u) << 16; return v.f;
}
__device__ __forceinline__ u16 f2bf(float f){
  u32 u = __float_as_uint(f);
  u32 r = u + 0x7FFFu + ((u >> 16) & 1u);   // RNE
  return (u16)(r >> 16);
}

// ---------------------------------------------------------------------------
// K0a: dtype detector on x. flag=1 => fp32 input.
// ---------------------------------------------------------------------------
__global__ void k_detect(const u16* __restrict__ x, u32* __restrict__ flag){
  __shared__ int cnt[256];
  const int t = threadIdx.x;
  int c = 0;
  #pragma unroll
  for(int i = 0; i < 4; i++){
    u16 v = x[t * 4 + i];
    int e = (v >> 7) & 0xFF;
    if(e >= 112 && e <= 134) c++;
  }
  cnt[t] = c;
  __syncthreads();
  for(int s = 128; s > 0; s >>= 1){
    if(t < s) cnt[t] += cnt[t + s];
    __syncthreads();
  }
  if(t == 0) *flag = (cnt[0] < 800) ? 1u : 0u;
}

// ---------------------------------------------------------------------------
// K0b: canonicalize to bf16 (8 elems/thread).
// ---------------------------------------------------------------------------
__global__ __launch_bounds__(256) void k_conv_bf(const void* __restrict__ src,
                                                 u16* __restrict__ dst, int n,
                                                 const u32* __restrict__ flag){
  const int i0 = (blockIdx.x * 256 + threadIdx.x) * 8;
  if(i0 >= n) return;
  const bool isf32 = (*flag != 0);
  if(isf32){
    const float4 a = *(const float4*)((const float*)src + i0);
    const float4 b = *(const float4*)((const float*)src + i0 + 4);
    uint4 o;
    o.x = (u32)f2bf(a.x) | ((u32)f2bf(a.y) << 16);
    o.y = (u32)f2bf(a.z) | ((u32)f2bf(a.w) << 16);
    o.z = (u32)f2bf(b.x) | ((u32)f2bf(b.y) << 16);
    o.w = (u32)f2bf(b.z) | ((u32)f2bf(b.w) << 16);
    *(uint4*)(dst + i0) = o;
  } else {
    *(uint4*)(dst + i0) = *(const uint4*)((const u16*)src + i0);
  }
}

// ---------------------------------------------------------------------------
// K0c: canonicalize to fp32 (4 elems/thread).
// ---------------------------------------------------------------------------
__global__ __launch_bounds__(256) void k_conv_f32(const void* __restrict__ src,
                                                  float* __restrict__ dst, int n,
                                                  const u32* __restrict__ flag){
  const int i0 = (blockIdx.x * 256 + threadIdx.x) * 4;
  if(i0 >= n) return;
  const bool isf32 = (*flag != 0);
  if(isf32){
    *(float4*)(dst + i0) = *(const float4*)((const float*)src + i0);
  } else {
    const uint2 a = *(const uint2*)((const u16*)src + i0);
    float4 o;
    o.x = bf2f((u16)(a.x & 0xFFFF)); o.y = bf2f((u16)(a.x >> 16));
    o.z = bf2f((u16)(a.y & 0xFFFF)); o.w = bf2f((u16)(a.y >> 16));
    *(float4*)(dst + i0) = o;
  }
}

// ---------------------------------------------------------------------------
// K0d: canonicalize to BOTH fp32 and bf16 (4 elems/thread) — for W_sa.
// ---------------------------------------------------------------------------
__global__ __launch_bounds__(256) void k_conv_both(const void* __restrict__ src,
                                                   float* __restrict__ dstf,
                                                   u16* __restrict__ dstb, int n,
                                                   const u32* __restrict__ flag){
  const int i0 = (blockIdx.x * 256 + threadIdx.x) * 4;
  if(i0 >= n) return;
  const bool isf32 = (*flag != 0);
  float4 o;
  if(isf32){
    o = *(const float4*)((const float*)src + i0);
  } else {
    const uint2 a = *(const uint2*)((const u16*)src + i0);
    o.x = bf2f((u16)(a.x & 0xFFFF)); o.y = bf2f((u16)(a.x >> 16));
    o.z = bf2f((u16)(a.y & 0xFFFF)); o.w = bf2f((u16)(a.y >> 16));
  }
  *(float4*)(dstf + i0) = o;
  uint2 pk;
  pk.x = (u32)f2bf(o.x) | ((u32)f2bf(o.y) << 16);
  pk.y = (u32)f2bf(o.z) | ((u32)f2bf(o.w) << 16);
  *(uint2*)(dstb + i0) = pk;
}

// ---------------------------------------------------------------------------
// K1: MFMA GEMM (unchanged from r8).
// ---------------------------------------------------------------------------
__device__ __forceinline__ bf16x8 ld_frag8(const u16* p){
  short4v lo = *(const short4v*)p;
  short4v hi = *(const short4v*)(p + 4);
  bf16x8 r;
  r[0]=lo[0]; r[1]=lo[1]; r[2]=lo[2]; r[3]=lo[3];
  r[4]=hi[0]; r[5]=hi[1]; r[6]=hi[2]; r[7]=hi[3];
  return r;
}

__global__ __launch_bounds__(256) void k_gemm_mfma(const u16* __restrict__ Wb,
                                                   const u16* __restrict__ xb,
                                                   u16* __restrict__ Y,
                                                   int rows_per_b){
  __shared__ u16 As[64][68];
  __shared__ u16 Ws[64][68];
  __shared__ float Cs[64][69];
  const int t = threadIdx.x;
  const int n0 = blockIdx.x * 64, m0 = blockIdx.y * 64, b = blockIdx.z;
  const int lane = t & 63, w = t >> 6;
  const int fm = lane & 15, fq = lane >> 4;
  f32x4 acc[4] = {};
  for(int kc = 0; kc < 256; kc += 64){
    #pragma unroll
    for(int half = 0; half < 2; half++){
      const int cl = half * 32 + (t >> 3);
      const int ns = (t & 7) * 8;
      const u16* sx = xb + (size_t)(b * 256 + kc + cl) * 4096 + n0 + ns;
      uint4 xv = *(const uint4*)sx;
      u16 e[8]; *(uint4*)e = xv;
      #pragma unroll
      for(int i = 0; i < 8; i++) As[ns + i][cl] = e[i];
    }
    {
      const int r = t >> 2, seg = (t & 3) * 16;
      const u16* sw = Wb + (size_t)(m0 + r) * 256 + kc + seg;
      uint2 w0 = *(const uint2*)sw;
      uint2 w1 = *(const uint2*)(sw + 4);
      uint2 w2 = *(const uint2*)(sw + 8);
      uint2 w3 = *(const uint2*)(sw + 12);
      *(uint2*)&Ws[r][seg]      = w0;
      *(uint2*)&Ws[r][seg + 4]  = w1;
      *(uint2*)&Ws[r][seg + 8]  = w2;
      *(uint2*)&Ws[r][seg + 12] = w3;
    }
    __syncthreads();
    #pragma unroll
    for(int ks = 0; ks < 2; ks++){
      const int kb = ks * 32 + fq * 8;
      bf16x8 a = ld_frag8(&As[w * 16 + fm][kb]);
      #pragma unroll
      for(int nt = 0; nt < 4; nt++){
        bf16x8 bb = ld_frag8(&Ws[nt * 16 + fm][kb]);
        acc[nt] = __builtin_amdgcn_mfma_f32_16x16x32_bf16(a, bb, acc[nt], 0, 0, 0);
      }
    }
    __syncthreads();
  }
  #pragma unroll
  for(int nt = 0; nt < 4; nt++){
    #pragma unroll
    for(int r = 0; r < 4; r++)
      Cs[nt * 16 + fm][w * 16 + fq * 4 + r] = acc[nt][r];
  }
  __syncthreads();
  {
    const int r = t >> 2, seg = (t & 3) * 16;
    uint4 o0, o1;
    u32 pk[8];
    #pragma unroll
    for(int i = 0; i < 8; i++)
      pk[i] = (u32)f2bf(Cs[r][seg + 2*i]) | ((u32)f2bf(Cs[r][seg + 2*i + 1]) << 16);
    o0.x = pk[0]; o0.y = pk[1]; o0.z = pk[2]; o0.w = pk[3];
    o1.x = pk[4]; o1.y = pk[5]; o1.z = pk[6]; o1.w = pk[7];
    u16* yp = Y + (size_t)(b * rows_per_b + m0 + r) * 4096 + n0 + seg;
    *(uint4*)yp = o0;
    *(uint4*)(yp + 8) = o1;
  }
}

// ---------------------------------------------------------------------------
// K2: split-K LDS-tiled xef partials (unchanged from r10).
// ---------------------------------------------------------------------------
__global__ __launch_bounds__(256) void k_xef8(const u16* __restrict__ xb,
                                              const float* __restrict__ EFf,
                                              float* __restrict__ xefp){
  __shared__ float At[32][68];
  __shared__ float Bt[64][72];
  const int t = threadIdx.x;
  const int c0 = blockIdx.x * 32, s = blockIdx.y, b = blockIdx.z;
  const int cc = t >> 3, p0 = (t & 7) * 8;
  float acc[8] = {};
  for(int n0 = s * 512; n0 < s * 512 + 512; n0 += 64){
    {
      const int r = t >> 3, k0 = (t & 7) * 8;
      const u16* sx = xb + (size_t)(b * 256 + c0 + r) * 4096 + n0 + k0;
      uint4 xv = *(const uint4*)sx;
      u16 e[8]; *(uint4*)e = xv;
      #pragma unroll
      for(int i = 0; i < 8; i++) At[r][k0 + i] = bf2f(e[i]);
      const int rk = t >> 2, pp = (t & 3) * 16;
      const float* se = EFf + (size_t)(n0 + rk) * 64 + pp;
      #pragma unroll
      for(int i = 0; i < 4; i++)
        *(float4*)&Bt[rk][pp + i * 4] = *(const float4*)(se + i * 4);
    }
    __syncthreads();
    #pragma unroll 8
    for(int kk = 0; kk < 64; kk++){
      const float a = At[cc][kk];
      const float4 b0 = *(const float4*)&Bt[kk][p0];
      const float4 b1 = *(const float4*)&Bt[kk][p0 + 4];
      acc[0] += a*b0.x; acc[1] += a*b0.y; acc[2] += a*b0.z; acc[3] += a*b0.w;
      acc[4] += a*b1.x; acc[5] += a*b1.y; acc[6] += a*b1.z; acc[7] += a*b1.w;
    }
    __syncthreads();
  }
  float* dst = xefp + ((size_t)s * 131072 + (size_t)(b * 256 + c0 + cc) * 64 + p0);
  #pragma unroll
  for(int i = 0; i < 8; i++) dst[i] = acc[i];
}

// ---------------------------------------------------------------------------
// K2b: reduce partials: xef[i] = sum_s xefp[s][i].
// ---------------------------------------------------------------------------
__global__ __launch_bounds__(256) void k_xred(const float* __restrict__ xefp,
                                              float* __restrict__ xef){
  const int i0 = (blockIdx.x * 256 + threadIdx.x) * 4;
  float4 a = *(const float4*)(xefp + i0);
  #pragma unroll
  for(int s = 1; s < 8; s++){
    const float4 v = *(const float4*)(xefp + (size_t)s * 131072 + i0);
    a.x += v.x; a.y += v.y; a.z += v.z; a.w += v.w;
  }
  *(float4*)(xef + i0) = a;
}

// ---------------------------------------------------------------------------
// K3: kvp[b, r, p] = sum_c W_sa[row_w(r), c] * xef[b, c, p]
// ---------------------------------------------------------------------------
__global__ __launch_bounds__(256) void k_kv4(const float* __restrict__ Wsaf,
                                             const float* __restrict__ xef,
                                             float* __restrict__ kvp){
  const int t = threadIdx.x;
  const int ri = t >> 6, p = t & 63;
  const int r = blockIdx.x * 4 + ri, b = blockIdx.y;
  const int row_w = (r < 256) ? (256 + r) : (512 + r);
  const float* wr = Wsaf + (size_t)row_w * 256;
  const float* xr = xef + (size_t)(b * 256) * 64 + p;
  float acc = 0.f;
  for(int c = 0; c < 256; c++)
    acc += wr[c] * xr[(size_t)c * 64];
  kvp[(size_t)(b * 512 + r) * 64 + p] = acc;
}

// ---------------------------------------------------------------------------
// K4: dst[b*256+r] = 1 / max(||row||_2, 1e-12), LDS tree reduction.
// ---------------------------------------------------------------------------
__global__ __launch_bounds__(256) void k_norm(const u16* __restrict__ src,
                                              float* __restrict__ dst,
                                              int stride_b, int row_off){
  __shared__ float red[256];
  const int r = blockIdx.x, b = blockIdx.y, t = threadIdx.x;
  const u16* row = src + (size_t)(b * stride_b + row_off + r) * 4096;
  float s = 0.f;
  #pragma unroll
  for(int i = 0; i < 16; i++){ float v = bf2f(row[t + 256 * i]); s += v * v; }
  red[t] = s;
  __syncthreads();
  for(int s2 = 128; s2 > 0; s2 >>= 1){
    if(t < s2) red[t] += red[t + s2];
    __syncthreads();
  }
  if(t == 0) dst[b * 256 + r] = 1.0f / fmaxf(sqrtf(red[0]), 1e-12f);
}

// ---------------------------------------------------------------------------
// K5 (new): MFMA Gram partials. Gp[s][b][h][j][e] = sum_{n in split} qc[j,n]*kc[e,n].
// D[j][e] = Q·K^T: first operand = Q rows (k-contiguous), second = K rows —
// both load naturally via ld_frag8, no LDS. Block (s,h,b), 4 waves; wave w
// owns 16x16 tile (j0 = (w>>1)*16, e0 = (w&1)*16), 16 chained MFMAs over 512 n.
// D mapping: lane l, reg r -> j = j0 + (l>>4)*4 + r, e = e0 + (l&15).
// ---------------------------------------------------------------------------
__global__ __launch_bounds__(256) void k_gram_mfma(const u16* __restrict__ y_sc,
                                                   float* __restrict__ Gp){
  const int t = threadIdx.x;
  const int s = blockIdx.x, h = blockIdx.y, b = blockIdx.z;
  const int w = t >> 6, lane = t & 63;
  const int fm = lane & 15, fq = lane >> 4;
  const int j0 = (w >> 1) * 16, e0 = (w & 1) * 16;
  const u16* qrow = y_sc + (size_t)(b * 768 + h * 32 + j0 + fm) * 4096;
  const u16* krow = y_sc + (size_t)(b * 768 + 256 + h * 32 + e0 + fm) * 4096;
  f32x4 acc = {};
  const int nb0 = s * 512 + fq * 8;
  #pragma unroll 4
  for(int it = 0; it < 16; it++){
    const int nb = nb0 + it * 32;
    bf16x8 a  = ld_frag8(qrow + nb);
    bf16x8 bb = ld_frag8(krow + nb);
    acc = __builtin_amdgcn_mfma_f32_16x16x32_bf16(a, bb, acc, 0, 0, 0);
  }
  float* dst = Gp + ((size_t)((s * 8 + b) * 8 + h) * 1024);
  #pragma unroll
  for(int r = 0; r < 4; r++)
    dst[(j0 + fq * 4 + r) * 32 + e0 + fm] = acc[r];
}

// ---------------------------------------------------------------------------
// K5b: attn[b][h][j][e] = softmax_e( (sum_s Gp) * invq[j] * invk[e] * temp[h] )
// ---------------------------------------------------------------------------
__global__ void k_softmax_ca(const float* __restrict__ Gp,
                             const float* __restrict__ invq,
                             const float* __restrict__ invk,
                             const float* __restrict__ temp,
                             float* __restrict__ attn){
  const int j = threadIdx.x, h = blockIdx.x, b = blockIdx.y;
  const float tm = temp[h];
  const float iq = invq[b * 256 + h * 32 + j];
  float v[32];
  float m = -1e30f;
  #pragma unroll
  for(int e = 0; e < 32; e++){
    float g = 0.f;
    #pragma unroll
    for(int s = 0; s < 8; s++)
      g += Gp[(size_t)s * 65536 + (size_t)(b * 8 + h) * 1024 + j * 32 + e];
    float val = g * iq * invk[b * 256 + h * 32 + e] * tm;
    v[e] = val; m = fmaxf(m, val);
  }
  float sum = 0.f;
  #pragma unroll
  for(int e = 0; e < 32; e++){ v[e] = __expf(v[e] - m); sum += v[e]; }
  const float inv = 1.0f / sum;
  #pragma unroll
  for(int e = 0; e < 32; e++) attn[(size_t)(b * 8 + h) * 1024 + j * 32 + e] = v[e] * inv;
}

// ---------------------------------------------------------------------------
// K6: spatial attention -> xsa[b][h][j][n] (bf16, natural layout).
// ---------------------------------------------------------------------------
__global__ __launch_bounds__(256) void k_sa8(const u16* __restrict__ q_sa,
                                             const float* __restrict__ kvp,
                                             const float* __restrict__ inv_sa,
                                             const float* __restrict__ temp2,
                                             u16* __restrict__ xsa){
  __shared__ float kp[2048];
  __shared__ float vp[2048];
  __shared__ float invl[32];
  const int t = threadIdx.x;
  const int ntile = blockIdx.x, h = blockIdx.y, b = blockIdx.z;
  {
    const float* ks = kvp + (size_t)(b * 512 + h * 32) * 64;
    const float* vs = kvp + (size_t)(b * 512 + 256 + h * 32) * 64;
    #pragma unroll
    for(int i = 0; i < 8; i++){
      kp[i * 256 + t] = ks[i * 256 + t];
      vp[i * 256 + t] = vs[i * 256 + t];
    }
    if(t < 32) invl[t] = inv_sa[b * 256 + h * 32 + t];
  }
  __syncthreads();
  const int n = ntile * 256 + t;
  float l[64];
  #pragma unroll
  for(int p = 0; p < 64; p++) l[p] = 0.f;
  for(int j = 0; j < 32; j++){
    const float qv = bf2f(q_sa[(size_t)(b * 256 + h * 32 + j) * 4096 + n]) * invl[j];
    const float4* k4 = (const float4*)&kp[j * 64];
    #pragma unroll
    for(int p4 = 0; p4 < 16; p4++){
      const float4 kv = k4[p4];
      l[p4*4+0] += qv*kv.x; l[p4*4+1] += qv*kv.y; l[p4*4+2] += qv*kv.z; l[p4*4+3] += qv*kv.w;
    }
  }
  const float tm = temp2[h];
  float m = -1e30f;
  #pragma unroll
  for(int p = 0; p < 64; p++){ l[p] *= tm; m = fmaxf(m, l[p]); }
  float sum = 0.f;
  #pragma unroll
  for(int p = 0; p < 64; p++){ l[p] = __expf(l[p] - m); sum += l[p]; }
  const float sinv = 1.0f / sum;
  for(int j = 0; j < 32; j++){
    const float4* v4 = (const float4*)&vp[j * 64];
    float s = 0.f;
    #pragma unroll
    for(int p4 = 0; p4 < 16; p4++){
      const float4 vv = v4[p4];
      s += l[p4*4+0]*vv.x + l[p4*4+1]*vv.y + l[p4*4+2]*vv.z + l[p4*4+3]*vv.w;
    }
    xsa[((size_t)(b * 8 + h) * 32 + j) * 4096 + n] = f2bf(s * sinv);
  }
}

// ---------------------------------------------------------------------------
// K7: tiled out-writer (unchanged from r9).
// ---------------------------------------------------------------------------
__global__ __launch_bounds__(256) void k_out2(const u16* __restrict__ y_sc,
                                              const float* __restrict__ attn,
                                              const u16* __restrict__ xsa,
                                              float* __restrict__ out){
  __shared__ u16 VcL[32][520];
  __shared__ u16 xs[32][16][34];
  __shared__ float arL[32][32];
  const int t = threadIdx.x;
  const int jg = blockIdx.x, hc = blockIdx.y, b = blockIdx.z;
  const int nn0 = jg * 512;
  {
    const float* ap = attn + (size_t)(b * 8 + hc) * 1024;
    #pragma unroll
    for(int i = 0; i < 4; i++) ((float*)arL)[t + 256 * i] = ap[t + 256 * i];
  }
  {
    const int e = t >> 3, ch = (t & 7) * 64;
    const u16* src = y_sc + (size_t)(b * 768 + 512 + hc * 32 + e) * 4096 + nn0 + ch;
    #pragma unroll
    for(int i = 0; i < 8; i++)
      *(uint4*)&VcL[e][ch + i * 8] = *(const uint4*)(src + i * 8);
  }
  #pragma unroll
  for(int rep = 0; rep < 2; rep++){
    const int s = rep * 256 + t;
    const int hj = s >> 4, nh = s & 15;
    const int h = hj & 7, jj = hj >> 3;
    const u16* src = xsa + ((size_t)(b * 8 + h) * 32 + jg * 4 + jj) * 4096 + nh * 256 + hc * 32;
    uint4 v0 = *(const uint4*)src;
    uint4 v1 = *(const uint4*)(src + 8);
    u16* dst = &xs[hj][nh][0];
    u32* d32 = (u32*)dst;
    d32[0] = v0.x; d32[1] = v0.y; d32[2] = v0.z; d32[3] = v0.w;
    d32[4] = v1.x; d32[5] = v1.y; d32[6] = v1.z; d32[7] = v1.w;
    uint4 v2 = *(const uint4*)(src + 16);
    uint4 v3 = *(const uint4*)(src + 24);
    d32[8]  = v2.x; d32[9]  = v2.y; d32[10] = v2.z; d32[11] = v2.w;
    d32[12] = v3.x; d32[13] = v3.y; d32[14] = v3.z; d32[15] = v3.w;
  }
  __syncthreads();
  const int nl0 = 2 * t;
  const int hj0 = nl0 >> 4, nh0 = nl0 & 15;
  for(int row = 0; row < 32; row++){
    float acc0 = 0.f, acc1 = 0.f;
    #pragma unroll
    for(int e = 0; e < 32; e++){
      const float a = arL[row][e];
      const u32 v = *(const u32*)&VcL[e][nl0];
      acc0 += a * bf2f((u16)(v & 0xFFFF));
      acc1 += a * bf2f((u16)(v >> 16));
    }
    const float sa0 = bf2f(xs[hj0][nh0][row]);
    const float sa1 = bf2f(xs[hj0][nh0 + 1][row]);
    float2 o; o.x = acc0 + sa0; o.y = acc1 + sa1;
    *(float2*)&out[(size_t)(b * 256 + hc * 32 + row) * 4096 + nn0 + nl0] = o;
  }
}

// ---------------------------------------------------------------------------
// Workspace layout (bytes), total ~95.2 MB (unchanged).
// ---------------------------------------------------------------------------
#define OFF_XB    ((size_t)0)           // u16 [8][256][4096] 16,777,216 (reused as xsa)
#define OFF_QSA   ((size_t)16777216)    // u16 [8][256][4096] 16,777,216
#define OFF_YSC   ((size_t)33554432)    // u16 [8][768][4096] 50,331,648
#define OFF_WSAF  ((size_t)83886080)    // f32 [1024][256]     1,048,576
#define OFF_WBSA  ((size_t)84934656)    // u16 [1024][256]       524,288
#define OFF_WBSC  ((size_t)85458944)    // u16 [1024][256]       524,288
#define OFF_EFF   ((size_t)85983232)    // f32 [4096][64]      1,048,576
#define OFF_XEF   ((size_t)87031808)    // f32 [8][256][64]      524,288
#define OFF_KVP   ((size_t)87556096)    // f32 [8][512][64]    1,048,576
#define OFF_ISA   ((size_t)88604672)    // f32 [8][256]            8,192
#define OFF_IQC   ((size_t)88612864)
#define OFF_IKC   ((size_t)88621056)
#define OFF_GP    ((size_t)88629248)    // f32 [8][8][8][32][32] 2,097,152
#define OFF_ATT   ((size_t)90726400)    // f32 [8][8][32][32]    262,144
#define OFF_TF    ((size_t)90988544)    // f32 [16]
#define OFF_FLAG  ((size_t)90988608)    // u32
#define OFF_XEFP  ((size_t)90992640)    // f32 [8][8][256][64] 4,194,304

extern "C" void kernel_launch(void* const* d_in, const int* in_sizes, int n_in,
                              void* d_out, int out_size, void* d_ws, size_t ws_size,
                              hipStream_t stream){
  (void)in_sizes; (void)n_in; (void)out_size; (void)ws_size;
  char* ws = (char*)d_ws;
  u16*   xb    = (u16*)  (ws + OFF_XB);
  u16*   xsa   = (u16*)  (ws + OFF_XB);    // overlay: xb dead after gemms/xef8
  u16*   q_sa  = (u16*)  (ws + OFF_QSA);
  u16*   y_sc  = (u16*)  (ws + OFF_YSC);
  float* Wsaf  = (float*)(ws + OFF_WSAF);
  u16*   WbSA  = (u16*)  (ws + OFF_WBSA);
  u16*   WbSC  = (u16*)  (ws + OFF_WBSC);
  float* EFf   = (float*)(ws + OFF_EFF);
  float* xef   = (float*)(ws + OFF_XEF);
  float* kvp   = (float*)(ws + OFF_KVP);
  float* invsa = (float*)(ws + OFF_ISA);
  float* invqc = (float*)(ws + OFF_IQC);
  float* invkc = (float*)(ws + OFF_IKC);
  float* Gp    = (float*)(ws + OFF_GP);
  float* attn  = (float*)(ws + OFF_ATT);
  float* tf    = (float*)(ws + OFF_TF);
  u32*   flag  = (u32*)  (ws + OFF_FLAG);
  float* xefp  = (float*)(ws + OFF_XEFP);
  float* out = (float*)d_out;

  // dtype detect + canonicalize
  k_detect<<<1, 256, 0, stream>>>((const u16*)d_in[0], flag);
  k_conv_bf  <<<4096, 256, 0, stream>>>(d_in[0], xb, 8388608, flag);          // x -> bf16
  k_conv_both<<<256,  256, 0, stream>>>(d_in[1], Wsaf, WbSA, 262144, flag);   // W_sa -> f32+bf16
  k_conv_f32 <<<256,  256, 0, stream>>>(d_in[2], EFf, 262144, flag);          // EF -> f32
  k_conv_bf  <<<128,  256, 0, stream>>>(d_in[4], WbSC, 262144, flag);         // W_sc -> bf16
  k_conv_f32 <<<1,    256, 0, stream>>>(d_in[3], tf,      8, flag);           // temp2_sa
  k_conv_f32 <<<1,    256, 0, stream>>>(d_in[5], tf + 8,  8, flag);           // temp_sc

  // QKV GEMMs (MFMA)
  k_gemm_mfma<<<dim3(64, 4, 8),  256, 0, stream>>>(WbSA, xb, q_sa, 256);
  k_gemm_mfma<<<dim3(64, 12, 8), 256, 0, stream>>>(WbSC, xb, y_sc, 768);
  // Linformer projection: split-K xef partials + reduce, then kvp
  k_xef8<<<dim3(8, 8, 8), 256, 0, stream>>>(xb, EFf, xefp);
  k_xred<<<128, 256, 0, stream>>>(xefp, xef);
  k_kv4 <<<dim3(128, 8), 256, 0, stream>>>(Wsaf, xef, kvp);
  // L2 norms (reciprocals)
  k_norm<<<dim3(256, 8), 256, 0, stream>>>(q_sa, invsa, 256, 0);
  k_norm<<<dim3(256, 8), 256, 0, stream>>>(y_sc, invqc, 768, 0);
  k_norm<<<dim3(256, 8), 256, 0, stream>>>(y_sc, invkc, 768, 256);
  // Channel attention matrix (MFMA gram)
  k_gram_mfma<<<dim3(8, 8, 8), 256, 0, stream>>>(y_sc, Gp);
  k_softmax_ca<<<dim3(8, 8), 32, 0, stream>>>(Gp, invqc, invkc, tf + 8, attn);
  // Spatial attention -> xsa, then tiled scramble-gather -> fp32 out
  k_sa8<<<dim3(16, 8, 8), 256, 0, stream>>>(q_sa, kvp, invsa, tf, xsa);
  k_out2<<<dim3(8, 8, 8), 256, 0, stream>>>(y_sc, attn, xsa, out);
}

// Round 12
// 290.286 us; speedup vs baseline: 2.9622x; 1.1277x over previous
//
#include <hip/hip_runtime.h>

typedef unsigned short u16;
typedef unsigned int   u32;

typedef __attribute__((ext_vector_type(4))) short short4v;
typedef __attribute__((ext_vector_type(8))) short bf16x8;  // 8 bf16 (4 VGPRs)
typedef __attribute__((ext_vector_type(4))) float f32x4;

// Problem: B=8, C=256, N=4096, heads=8, d=32, P=64. Inputs fp32 (auto-detect),
// output FP32. r8: MFMA GEMMs. r9: tiled out. r10: split-K xef. r11: MFMA gram.
// r12: full-MFMA spatial attention (QK=1 MFMA K=32, softmax via shfl, PV=2 MFMA).

__device__ __forceinline__ float bf2f(u16 u){
  union { u32 i; float f; } v; v.i = ((u32)u) << 16; return v.f;
}
__device__ __forceinline__ u16 f2bf(float f){
  u32 u = __float_as_uint(f);
  u32 r = u + 0x7FFFu + ((u >> 16) & 1u);   // RNE
  return (u16)(r >> 16);
}

// ---------------------------------------------------------------------------
// K0a: dtype detector on x. flag=1 => fp32 input.
// ---------------------------------------------------------------------------
__global__ void k_detect(const u16* __restrict__ x, u32* __restrict__ flag){
  __shared__ int cnt[256];
  const int t = threadIdx.x;
  int c = 0;
  #pragma unroll
  for(int i = 0; i < 4; i++){
    u16 v = x[t * 4 + i];
    int e = (v >> 7) & 0xFF;
    if(e >= 112 && e <= 134) c++;
  }
  cnt[t] = c;
  __syncthreads();
  for(int s = 128; s > 0; s >>= 1){
    if(t < s) cnt[t] += cnt[t + s];
    __syncthreads();
  }
  if(t == 0) *flag = (cnt[0] < 800) ? 1u : 0u;
}

// ---------------------------------------------------------------------------
// K0b: canonicalize to bf16 (8 elems/thread).
// ---------------------------------------------------------------------------
__global__ __launch_bounds__(256) void k_conv_bf(const void* __restrict__ src,
                                                 u16* __restrict__ dst, int n,
                                                 const u32* __restrict__ flag){
  const int i0 = (blockIdx.x * 256 + threadIdx.x) * 8;
  if(i0 >= n) return;
  const bool isf32 = (*flag != 0);
  if(isf32){
    const float4 a = *(const float4*)((const float*)src + i0);
    const float4 b = *(const float4*)((const float*)src + i0 + 4);
    uint4 o;
    o.x = (u32)f2bf(a.x) | ((u32)f2bf(a.y) << 16);
    o.y = (u32)f2bf(a.z) | ((u32)f2bf(a.w) << 16);
    o.z = (u32)f2bf(b.x) | ((u32)f2bf(b.y) << 16);
    o.w = (u32)f2bf(b.z) | ((u32)f2bf(b.w) << 16);
    *(uint4*)(dst + i0) = o;
  } else {
    *(uint4*)(dst + i0) = *(const uint4*)((const u16*)src + i0);
  }
}

// ---------------------------------------------------------------------------
// K0c: canonicalize to fp32 (4 elems/thread).
// ---------------------------------------------------------------------------
__global__ __launch_bounds__(256) void k_conv_f32(const void* __restrict__ src,
                                                  float* __restrict__ dst, int n,
                                                  const u32* __restrict__ flag){
  const int i0 = (blockIdx.x * 256 + threadIdx.x) * 4;
  if(i0 >= n) return;
  const bool isf32 = (*flag != 0);
  if(isf32){
    *(float4*)(dst + i0) = *(const float4*)((const float*)src + i0);
  } else {
    const uint2 a = *(const uint2*)((const u16*)src + i0);
    float4 o;
    o.x = bf2f((u16)(a.x & 0xFFFF)); o.y = bf2f((u16)(a.x >> 16));
    o.z = bf2f((u16)(a.y & 0xFFFF)); o.w = bf2f((u16)(a.y >> 16));
    *(float4*)(dst + i0) = o;
  }
}

// ---------------------------------------------------------------------------
// K0d: canonicalize to BOTH fp32 and bf16 (4 elems/thread) — for W_sa.
// ---------------------------------------------------------------------------
__global__ __launch_bounds__(256) void k_conv_both(const void* __restrict__ src,
                                                   float* __restrict__ dstf,
                                                   u16* __restrict__ dstb, int n,
                                                   const u32* __restrict__ flag){
  const int i0 = (blockIdx.x * 256 + threadIdx.x) * 4;
  if(i0 >= n) return;
  const bool isf32 = (*flag != 0);
  float4 o;
  if(isf32){
    o = *(const float4*)((const float*)src + i0);
  } else {
    const uint2 a = *(const uint2*)((const u16*)src + i0);
    o.x = bf2f((u16)(a.x & 0xFFFF)); o.y = bf2f((u16)(a.x >> 16));
    o.z = bf2f((u16)(a.y & 0xFFFF)); o.w = bf2f((u16)(a.y >> 16));
  }
  *(float4*)(dstf + i0) = o;
  uint2 pk;
  pk.x = (u32)f2bf(o.x) | ((u32)f2bf(o.y) << 16);
  pk.y = (u32)f2bf(o.z) | ((u32)f2bf(o.w) << 16);
  *(uint2*)(dstb + i0) = pk;
}

// ---------------------------------------------------------------------------
// K1: MFMA GEMM (unchanged from r8).
// ---------------------------------------------------------------------------
__device__ __forceinline__ bf16x8 ld_frag8(const u16* p){
  short4v lo = *(const short4v*)p;
  short4v hi = *(const short4v*)(p + 4);
  bf16x8 r;
  r[0]=lo[0]; r[1]=lo[1]; r[2]=lo[2]; r[3]=lo[3];
  r[4]=hi[0]; r[5]=hi[1]; r[6]=hi[2]; r[7]=hi[3];
  return r;
}

__global__ __launch_bounds__(256) void k_gemm_mfma(const u16* __restrict__ Wb,
                                                   const u16* __restrict__ xb,
                                                   u16* __restrict__ Y,
                                                   int rows_per_b){
  __shared__ u16 As[64][68];
  __shared__ u16 Ws[64][68];
  __shared__ float Cs[64][69];
  const int t = threadIdx.x;
  const int n0 = blockIdx.x * 64, m0 = blockIdx.y * 64, b = blockIdx.z;
  const int lane = t & 63, w = t >> 6;
  const int fm = lane & 15, fq = lane >> 4;
  f32x4 acc[4] = {};
  for(int kc = 0; kc < 256; kc += 64){
    #pragma unroll
    for(int half = 0; half < 2; half++){
      const int cl = half * 32 + (t >> 3);
      const int ns = (t & 7) * 8;
      const u16* sx = xb + (size_t)(b * 256 + kc + cl) * 4096 + n0 + ns;
      uint4 xv = *(const uint4*)sx;
      u16 e[8]; *(uint4*)e = xv;
      #pragma unroll
      for(int i = 0; i < 8; i++) As[ns + i][cl] = e[i];
    }
    {
      const int r = t >> 2, seg = (t & 3) * 16;
      const u16* sw = Wb + (size_t)(m0 + r) * 256 + kc + seg;
      uint2 w0 = *(const uint2*)sw;
      uint2 w1 = *(const uint2*)(sw + 4);
      uint2 w2 = *(const uint2*)(sw + 8);
      uint2 w3 = *(const uint2*)(sw + 12);
      *(uint2*)&Ws[r][seg]      = w0;
      *(uint2*)&Ws[r][seg + 4]  = w1;
      *(uint2*)&Ws[r][seg + 8]  = w2;
      *(uint2*)&Ws[r][seg + 12] = w3;
    }
    __syncthreads();
    #pragma unroll
    for(int ks = 0; ks < 2; ks++){
      const int kb = ks * 32 + fq * 8;
      bf16x8 a = ld_frag8(&As[w * 16 + fm][kb]);
      #pragma unroll
      for(int nt = 0; nt < 4; nt++){
        bf16x8 bb = ld_frag8(&Ws[nt * 16 + fm][kb]);
        acc[nt] = __builtin_amdgcn_mfma_f32_16x16x32_bf16(a, bb, acc[nt], 0, 0, 0);
      }
    }
    __syncthreads();
  }
  #pragma unroll
  for(int nt = 0; nt < 4; nt++){
    #pragma unroll
    for(int r = 0; r < 4; r++)
      Cs[nt * 16 + fm][w * 16 + fq * 4 + r] = acc[nt][r];
  }
  __syncthreads();
  {
    const int r = t >> 2, seg = (t & 3) * 16;
    uint4 o0, o1;
    u32 pk[8];
    #pragma unroll
    for(int i = 0; i < 8; i++)
      pk[i] = (u32)f2bf(Cs[r][seg + 2*i]) | ((u32)f2bf(Cs[r][seg + 2*i + 1]) << 16);
    o0.x = pk[0]; o0.y = pk[1]; o0.z = pk[2]; o0.w = pk[3];
    o1.x = pk[4]; o1.y = pk[5]; o1.z = pk[6]; o1.w = pk[7];
    u16* yp = Y + (size_t)(b * rows_per_b + m0 + r) * 4096 + n0 + seg;
    *(uint4*)yp = o0;
    *(uint4*)(yp + 8) = o1;
  }
}

// ---------------------------------------------------------------------------
// K2: split-K LDS-tiled xef partials (unchanged from r10).
// ---------------------------------------------------------------------------
__global__ __launch_bounds__(256) void k_xef8(const u16* __restrict__ xb,
                                              const float* __restrict__ EFf,
                                              float* __restrict__ xefp){
  __shared__ float At[32][68];
  __shared__ float Bt[64][72];
  const int t = threadIdx.x;
  const int c0 = blockIdx.x * 32, s = blockIdx.y, b = blockIdx.z;
  const int cc = t >> 3, p0 = (t & 7) * 8;
  float acc[8] = {};
  for(int n0 = s * 512; n0 < s * 512 + 512; n0 += 64){
    {
      const int r = t >> 3, k0 = (t & 7) * 8;
      const u16* sx = xb + (size_t)(b * 256 + c0 + r) * 4096 + n0 + k0;
      uint4 xv = *(const uint4*)sx;
      u16 e[8]; *(uint4*)e = xv;
      #pragma unroll
      for(int i = 0; i < 8; i++) At[r][k0 + i] = bf2f(e[i]);
      const int rk = t >> 2, pp = (t & 3) * 16;
      const float* se = EFf + (size_t)(n0 + rk) * 64 + pp;
      #pragma unroll
      for(int i = 0; i < 4; i++)
        *(float4*)&Bt[rk][pp + i * 4] = *(const float4*)(se + i * 4);
    }
    __syncthreads();
    #pragma unroll 8
    for(int kk = 0; kk < 64; kk++){
      const float a = At[cc][kk];
      const float4 b0 = *(const float4*)&Bt[kk][p0];
      const float4 b1 = *(const float4*)&Bt[kk][p0 + 4];
      acc[0] += a*b0.x; acc[1] += a*b0.y; acc[2] += a*b0.z; acc[3] += a*b0.w;
      acc[4] += a*b1.x; acc[5] += a*b1.y; acc[6] += a*b1.z; acc[7] += a*b1.w;
    }
    __syncthreads();
  }
  float* dst = xefp + ((size_t)s * 131072 + (size_t)(b * 256 + c0 + cc) * 64 + p0);
  #pragma unroll
  for(int i = 0; i < 8; i++) dst[i] = acc[i];
}

// ---------------------------------------------------------------------------
// K2b: reduce partials: xef[i] = sum_s xefp[s][i].
// ---------------------------------------------------------------------------
__global__ __launch_bounds__(256) void k_xred(const float* __restrict__ xefp,
                                              float* __restrict__ xef){
  const int i0 = (blockIdx.x * 256 + threadIdx.x) * 4;
  float4 a = *(const float4*)(xefp + i0);
  #pragma unroll
  for(int s = 1; s < 8; s++){
    const float4 v = *(const float4*)(xefp + (size_t)s * 131072 + i0);
    a.x += v.x; a.y += v.y; a.z += v.z; a.w += v.w;
  }
  *(float4*)(xef + i0) = a;
}

// ---------------------------------------------------------------------------
// K3 (new): kvp -> bf16 kpT/vpb for MFMA k_sa.
// r in [0,256): k rows (W_sa 256:512), scaled by invsa (q-norm folded into k):
//   kpT[(b*8+h)*64+p][j] = bf16( (sum_c W*xef) * invsa[b*256+r] ), h=r>>5, j=r&31
// r in [256,512): v rows (W_sa 768:1024):
//   vpb[(b*8+h)*32+jv][p] = bf16( sum_c W*xef ), rv=r-256, h=rv>>5, jv=rv&31
// ---------------------------------------------------------------------------
__global__ __launch_bounds__(256) void k_kv4b(const float* __restrict__ Wsaf,
                                              const float* __restrict__ xef,
                                              const float* __restrict__ invsa,
                                              u16* __restrict__ kpT,
                                              u16* __restrict__ vpb){
  const int t = threadIdx.x;
  const int ri = t >> 6, p = t & 63;
  const int r = blockIdx.x * 4 + ri, b = blockIdx.y;
  const int row_w = (r < 256) ? (256 + r) : (512 + r);
  const float* wr = Wsaf + (size_t)row_w * 256;
  const float* xr = xef + (size_t)(b * 256) * 64 + p;
  float acc = 0.f;
  for(int c = 0; c < 256; c++)
    acc += wr[c] * xr[(size_t)c * 64];
  if(r < 256){
    const float sc = invsa[b * 256 + r];
    kpT[((size_t)(b * 8 + (r >> 5)) * 64 + p) * 32 + (r & 31)] = f2bf(acc * sc);
  } else {
    const int rv = r - 256;
    vpb[((size_t)(b * 8 + (rv >> 5)) * 32 + (rv & 31)) * 64 + p] = f2bf(acc);
  }
}

// ---------------------------------------------------------------------------
// K4: dst[b*256+r] = 1 / max(||row||_2, 1e-12), LDS tree reduction.
// ---------------------------------------------------------------------------
__global__ __launch_bounds__(256) void k_norm(const u16* __restrict__ src,
                                              float* __restrict__ dst,
                                              int stride_b, int row_off){
  __shared__ float red[256];
  const int r = blockIdx.x, b = blockIdx.y, t = threadIdx.x;
  const u16* row = src + (size_t)(b * stride_b + row_off + r) * 4096;
  float s = 0.f;
  #pragma unroll
  for(int i = 0; i < 16; i++){ float v = bf2f(row[t + 256 * i]); s += v * v; }
  red[t] = s;
  __syncthreads();
  for(int s2 = 128; s2 > 0; s2 >>= 1){
    if(t < s2) red[t] += red[t + s2];
    __syncthreads();
  }
  if(t == 0) dst[b * 256 + r] = 1.0f / fmaxf(sqrtf(red[0]), 1e-12f);
}

// ---------------------------------------------------------------------------
// K5: MFMA Gram partials (unchanged from r11).
// ---------------------------------------------------------------------------
__global__ __launch_bounds__(256) void k_gram_mfma(const u16* __restrict__ y_sc,
                                                   float* __restrict__ Gp){
  const int t = threadIdx.x;
  const int s = blockIdx.x, h = blockIdx.y, b = blockIdx.z;
  const int w = t >> 6, lane = t & 63;
  const int fm = lane & 15, fq = lane >> 4;
  const int j0 = (w >> 1) * 16, e0 = (w & 1) * 16;
  const u16* qrow = y_sc + (size_t)(b * 768 + h * 32 + j0 + fm) * 4096;
  const u16* krow = y_sc + (size_t)(b * 768 + 256 + h * 32 + e0 + fm) * 4096;
  f32x4 acc = {};
  const int nb0 = s * 512 + fq * 8;
  #pragma unroll 4
  for(int it = 0; it < 16; it++){
    const int nb = nb0 + it * 32;
    bf16x8 a  = ld_frag8(qrow + nb);
    bf16x8 bb = ld_frag8(krow + nb);
    acc = __builtin_amdgcn_mfma_f32_16x16x32_bf16(a, bb, acc, 0, 0, 0);
  }
  float* dst = Gp + ((size_t)((s * 8 + b) * 8 + h) * 1024);
  #pragma unroll
  for(int r = 0; r < 4; r++)
    dst[(j0 + fq * 4 + r) * 32 + e0 + fm] = acc[r];
}

// ---------------------------------------------------------------------------
// K5b: channel softmax (unchanged).
// ---------------------------------------------------------------------------
__global__ void k_softmax_ca(const float* __restrict__ Gp,
                             const float* __restrict__ invq,
                             const float* __restrict__ invk,
                             const float* __restrict__ temp,
                             float* __restrict__ attn){
  const int j = threadIdx.x, h = blockIdx.x, b = blockIdx.y;
  const float tm = temp[h];
  const float iq = invq[b * 256 + h * 32 + j];
  float v[32];
  float m = -1e30f;
  #pragma unroll
  for(int e = 0; e < 32; e++){
    float g = 0.f;
    #pragma unroll
    for(int s = 0; s < 8; s++)
      g += Gp[(size_t)s * 65536 + (size_t)(b * 8 + h) * 1024 + j * 32 + e];
    float val = g * iq * invk[b * 256 + h * 32 + e] * tm;
    v[e] = val; m = fmaxf(m, val);
  }
  float sum = 0.f;
  #pragma unroll
  for(int e = 0; e < 32; e++){ v[e] = __expf(v[e] - m); sum += v[e]; }
  const float inv = 1.0f / sum;
  #pragma unroll
  for(int e = 0; e < 32; e++) attn[(size_t)(b * 8 + h) * 1024 + j * 32 + e] = v[e] * inv;
}

// ---------------------------------------------------------------------------
// K6 (new): full-MFMA spatial attention -> xsa[b][h][j][n].
// Block = (ntile 64 n, h, b), 4 waves; wave w owns n-rows w*16..+16.
//   QK: D[n][p] = sum_j q^T[n][j] * kpT[p][j]  (K=32, 1 MFMA per 16x16 p-tile;
//       q-norm pre-folded into kpT).
//   softmax over p: rows live on fixed-fq lane groups -> width-16 shfl_xor.
//   P (unnormalized bf16) -> Ps (wave-private rows, no barrier needed).
//   PV: D2[n][jv] = sum_p P[n][p] * vpb[jv][p]  (K=64, 2 MFMAs per jv-tile).
//   Epilogue: *sinv per n-row, LDS transpose, coalesced store.
// ---------------------------------------------------------------------------
__global__ __launch_bounds__(256) void k_sa_mfma(const u16* __restrict__ q_sa,
                                                 const u16* __restrict__ kpT,
                                                 const u16* __restrict__ vpb,
                                                 const float* __restrict__ temp2,
                                                 u16* __restrict__ xsa){
  __shared__ u16 As[64][36];    // [n][j]  q^T tile
  __shared__ u16 Ks[64][36];    // [p][j]  scaled k_proj^T
  __shared__ u16 Vs[32][68];    // [jv][p] v_proj
  __shared__ u16 Ps[64][68];    // [n][p]  unnormalized probs (wave-private rows)
  __shared__ u16 Cs[32][68];    // [jv][n] output transpose
  const int t = threadIdx.x;
  const int ntile = blockIdx.x, h = blockIdx.y, b = blockIdx.z;
  const int n0 = ntile * 64;
  const int w = t >> 6, lane = t & 63;
  const int fm = lane & 15, fq = lane >> 4;
  // stage As: q rows j (n-contig) -> As[n][j]
  {
    const int j = t >> 3, ns = (t & 7) * 8;
    const u16* src = q_sa + (size_t)(b * 256 + h * 32 + j) * 4096 + n0 + ns;
    uint4 v = *(const uint4*)src;
    u16 e[8]; *(uint4*)e = v;
    #pragma unroll
    for(int i = 0; i < 8; i++) As[ns + i][j] = e[i];
  }
  // stage Ks: 64 p-rows x 32 j (contig)
  {
    const int p = t >> 2, jb = (t & 3) * 8;
    *(uint4*)&Ks[p][jb] =
      *(const uint4*)(kpT + ((size_t)(b * 8 + h) * 64 + p) * 32 + jb);
  }
  // stage Vs: 32 jv-rows x 64 p (contig)
  {
    const int jv = t >> 3, ps = (t & 7) * 8;
    *(uint4*)&Vs[jv][ps] =
      *(const uint4*)(vpb + ((size_t)(b * 8 + h) * 32 + jv) * 64 + ps);
  }
  __syncthreads();
  // QK
  bf16x8 a = ld_frag8(&As[w * 16 + fm][fq * 8]);
  f32x4 lg[4];
  #pragma unroll
  for(int pt = 0; pt < 4; pt++){
    bf16x8 bk = ld_frag8(&Ks[pt * 16 + fm][fq * 8]);
    f32x4 z = {};
    lg[pt] = __builtin_amdgcn_mfma_f32_16x16x32_bf16(a, bk, z, 0, 0, 0);
  }
  const float tm = temp2[h];
  float sinv[4];
  #pragma unroll
  for(int r = 0; r < 4; r++){
    float v0 = lg[0][r]*tm, v1 = lg[1][r]*tm, v2 = lg[2][r]*tm, v3 = lg[3][r]*tm;
    float mx = fmaxf(fmaxf(v0, v1), fmaxf(v2, v3));
    #pragma unroll
    for(int m = 1; m < 16; m <<= 1) mx = fmaxf(mx, __shfl_xor(mx, m, 16));
    v0 = __expf(v0 - mx); v1 = __expf(v1 - mx);
    v2 = __expf(v2 - mx); v3 = __expf(v3 - mx);
    float s = v0 + v1 + v2 + v3;
    #pragma unroll
    for(int m = 1; m < 16; m <<= 1) s += __shfl_xor(s, m, 16);
    sinv[r] = 1.0f / s;
    const int nrow = w * 16 + fq * 4 + r;
    Ps[nrow][fm]      = f2bf(v0);
    Ps[nrow][16 + fm] = f2bf(v1);
    Ps[nrow][32 + fm] = f2bf(v2);
    Ps[nrow][48 + fm] = f2bf(v3);
  }
  // PV — each wave reads only its own Ps rows; in-wave lgkmcnt ordering suffices
  f32x4 o[2] = {};
  #pragma unroll
  for(int ks = 0; ks < 2; ks++){
    bf16x8 ap = ld_frag8(&Ps[w * 16 + fm][ks * 32 + fq * 8]);
    #pragma unroll
    for(int jt = 0; jt < 2; jt++){
      bf16x8 bv = ld_frag8(&Vs[jt * 16 + fm][ks * 32 + fq * 8]);
      o[jt] = __builtin_amdgcn_mfma_f32_16x16x32_bf16(ap, bv, o[jt], 0, 0, 0);
    }
  }
  #pragma unroll
  for(int jt = 0; jt < 2; jt++)
    #pragma unroll
    for(int r = 0; r < 4; r++)
      Cs[jt * 16 + fm][w * 16 + fq * 4 + r] = f2bf(o[jt][r] * sinv[r]);
  __syncthreads();
  {
    const int jv = t >> 3, ns = (t & 7) * 8;
    u16 e[8];
    #pragma unroll
    for(int i = 0; i < 8; i++) e[i] = Cs[jv][ns + i];
    *(uint4*)(xsa + ((size_t)(b * 8 + h) * 32 + jv) * 4096 + n0 + ns) = *(uint4*)e;
  }
}

// ---------------------------------------------------------------------------
// K7: tiled out-writer (unchanged from r9).
// ---------------------------------------------------------------------------
__global__ __launch_bounds__(256) void k_out2(const u16* __restrict__ y_sc,
                                              const float* __restrict__ attn,
                                              const u16* __restrict__ xsa,
                                              float* __restrict__ out){
  __shared__ u16 VcL[32][520];
  __shared__ u16 xs[32][16][34];
  __shared__ float arL[32][32];
  const int t = threadIdx.x;
  const int jg = blockIdx.x, hc = blockIdx.y, b = blockIdx.z;
  const int nn0 = jg * 512;
  {
    const float* ap = attn + (size_t)(b * 8 + hc) * 1024;
    #pragma unroll
    for(int i = 0; i < 4; i++) ((float*)arL)[t + 256 * i] = ap[t + 256 * i];
  }
  {
    const int e = t >> 3, ch = (t & 7) * 64;
    const u16* src = y_sc + (size_t)(b * 768 + 512 + hc * 32 + e) * 4096 + nn0 + ch;
    #pragma unroll
    for(int i = 0; i < 8; i++)
      *(uint4*)&VcL[e][ch + i * 8] = *(const uint4*)(src + i * 8);
  }
  #pragma unroll
  for(int rep = 0; rep < 2; rep++){
    const int s = rep * 256 + t;
    const int hj = s >> 4, nh = s & 15;
    const int h = hj & 7, jj = hj >> 3;
    const u16* src = xsa + ((size_t)(b * 8 + h) * 32 + jg * 4 + jj) * 4096 + nh * 256 + hc * 32;
    uint4 v0 = *(const uint4*)src;
    uint4 v1 = *(const uint4*)(src + 8);
    u16* dst = &xs[hj][nh][0];
    u32* d32 = (u32*)dst;
    d32[0] = v0.x; d32[1] = v0.y; d32[2] = v0.z; d32[3] = v0.w;
    d32[4] = v1.x; d32[5] = v1.y; d32[6] = v1.z; d32[7] = v1.w;
    uint4 v2 = *(const uint4*)(src + 16);
    uint4 v3 = *(const uint4*)(src + 24);
    d32[8]  = v2.x; d32[9]  = v2.y; d32[10] = v2.z; d32[11] = v2.w;
    d32[12] = v3.x; d32[13] = v3.y; d32[14] = v3.z; d32[15] = v3.w;
  }
  __syncthreads();
  const int nl0 = 2 * t;
  const int hj0 = nl0 >> 4, nh0 = nl0 & 15;
  for(int row = 0; row < 32; row++){
    float acc0 = 0.f, acc1 = 0.f;
    #pragma unroll
    for(int e = 0; e < 32; e++){
      const float a = arL[row][e];
      const u32 v = *(const u32*)&VcL[e][nl0];
      acc0 += a * bf2f((u16)(v & 0xFFFF));
      acc1 += a * bf2f((u16)(v >> 16));
    }
    const float sa0 = bf2f(xs[hj0][nh0][row]);
    const float sa1 = bf2f(xs[hj0][nh0 + 1][row]);
    float2 o; o.x = acc0 + sa0; o.y = acc1 + sa1;
    *(float2*)&out[(size_t)(b * 256 + hc * 32 + row) * 4096 + nn0 + nl0] = o;
  }
}

// ---------------------------------------------------------------------------
// Workspace layout (bytes), total ~95.2 MB. KVP region reused for bf16 kpT/vpb.
// ---------------------------------------------------------------------------
#define OFF_XB    ((size_t)0)           // u16 [8][256][4096] 16,777,216 (reused as xsa)
#define OFF_QSA   ((size_t)16777216)    // u16 [8][256][4096] 16,777,216
#define OFF_YSC   ((size_t)33554432)    // u16 [8][768][4096] 50,331,648
#define OFF_WSAF  ((size_t)83886080)    // f32 [1024][256]     1,048,576
#define OFF_WBSA  ((size_t)84934656)    // u16 [1024][256]       524,288
#define OFF_WBSC  ((size_t)85458944)    // u16 [1024][256]       524,288
#define OFF_EFF   ((size_t)85983232)    // f32 [4096][64]      1,048,576
#define OFF_XEF   ((size_t)87031808)    // f32 [8][256][64]      524,288
#define OFF_KPT   ((size_t)87556096)    // u16 [8][8][64][32]    262,144
#define OFF_VPB   ((size_t)87818240)    // u16 [8][8][32][64]    262,144
#define OFF_ISA   ((size_t)88604672)    // f32 [8][256]            8,192
#define OFF_IQC   ((size_t)88612864)
#define OFF_IKC   ((size_t)88621056)
#define OFF_GP    ((size_t)88629248)    // f32 [8][8][8][32][32] 2,097,152
#define OFF_ATT   ((size_t)90726400)    // f32 [8][8][32][32]    262,144
#define OFF_TF    ((size_t)90988544)    // f32 [16]
#define OFF_FLAG  ((size_t)90988608)    // u32
#define OFF_XEFP  ((size_t)90992640)    // f32 [8][8][256][64] 4,194,304

extern "C" void kernel_launch(void* const* d_in, const int* in_sizes, int n_in,
                              void* d_out, int out_size, void* d_ws, size_t ws_size,
                              hipStream_t stream){
  (void)in_sizes; (void)n_in; (void)out_size; (void)ws_size;
  char* ws = (char*)d_ws;
  u16*   xb    = (u16*)  (ws + OFF_XB);
  u16*   xsa   = (u16*)  (ws + OFF_XB);    // overlay: xb dead after gemms/xef8
  u16*   q_sa  = (u16*)  (ws + OFF_QSA);
  u16*   y_sc  = (u16*)  (ws + OFF_YSC);
  float* Wsaf  = (float*)(ws + OFF_WSAF);
  u16*   WbSA  = (u16*)  (ws + OFF_WBSA);
  u16*   WbSC  = (u16*)  (ws + OFF_WBSC);
  float* EFf   = (float*)(ws + OFF_EFF);
  float* xef   = (float*)(ws + OFF_XEF);
  u16*   kpT   = (u16*)  (ws + OFF_KPT);
  u16*   vpb   = (u16*)  (ws + OFF_VPB);
  float* invsa = (float*)(ws + OFF_ISA);
  float* invqc = (float*)(ws + OFF_IQC);
  float* invkc = (float*)(ws + OFF_IKC);
  float* Gp    = (float*)(ws + OFF_GP);
  float* attn  = (float*)(ws + OFF_ATT);
  float* tf    = (float*)(ws + OFF_TF);
  u32*   flag  = (u32*)  (ws + OFF_FLAG);
  float* xefp  = (float*)(ws + OFF_XEFP);
  float* out = (float*)d_out;

  // dtype detect + canonicalize
  k_detect<<<1, 256, 0, stream>>>((const u16*)d_in[0], flag);
  k_conv_bf  <<<4096, 256, 0, stream>>>(d_in[0], xb, 8388608, flag);          // x -> bf16
  k_conv_both<<<256,  256, 0, stream>>>(d_in[1], Wsaf, WbSA, 262144, flag);   // W_sa -> f32+bf16
  k_conv_f32 <<<256,  256, 0, stream>>>(d_in[2], EFf, 262144, flag);          // EF -> f32
  k_conv_bf  <<<128,  256, 0, stream>>>(d_in[4], WbSC, 262144, flag);         // W_sc -> bf16
  k_conv_f32 <<<1,    256, 0, stream>>>(d_in[3], tf,      8, flag);           // temp2_sa
  k_conv_f32 <<<1,    256, 0, stream>>>(d_in[5], tf + 8,  8, flag);           // temp_sc

  // QKV GEMMs (MFMA)
  k_gemm_mfma<<<dim3(64, 4, 8),  256, 0, stream>>>(WbSA, xb, q_sa, 256);
  k_gemm_mfma<<<dim3(64, 12, 8), 256, 0, stream>>>(WbSC, xb, y_sc, 768);
  // Linformer projection: split-K xef partials + reduce
  k_xef8<<<dim3(8, 8, 8), 256, 0, stream>>>(xb, EFf, xefp);
  k_xred<<<128, 256, 0, stream>>>(xefp, xef);
  // L2 norms (invsa needed by k_kv4b for q-norm folding)
  k_norm<<<dim3(256, 8), 256, 0, stream>>>(q_sa, invsa, 256, 0);
  k_norm<<<dim3(256, 8), 256, 0, stream>>>(y_sc, invqc, 768, 0);
  k_norm<<<dim3(256, 8), 256, 0, stream>>>(y_sc, invkc, 768, 256);
  // kpT (scaled) + vpb, bf16
  k_kv4b<<<dim3(128, 8), 256, 0, stream>>>(Wsaf, xef, invsa, kpT, vpb);
  // Channel attention matrix (MFMA gram) + softmax
  k_gram_mfma<<<dim3(8, 8, 8), 256, 0, stream>>>(y_sc, Gp);
  k_softmax_ca<<<dim3(8, 8), 32, 0, stream>>>(Gp, invqc, invkc, tf + 8, attn);
  // Spatial attention (full MFMA) -> xsa, then tiled scramble-gather -> fp32 out
  k_sa_mfma<<<dim3(64, 8, 8), 256, 0, stream>>>(q_sa, kpT, vpb, tf, xsa);
  k_out2<<<dim3(8, 8, 8), 256, 0, stream>>>(y_sc, attn, xsa, out);
}